// Round 1
// baseline (1972.488 us; speedup 1.0000x reference)
//
#include <hip/hip_runtime.h>
#include <hip/hip_bf16.h>
#include <stdint.h>

// Problem constants
#define BB 2
#define SS 2048
#define DD 4096
#define HH 32
#define HDD 128

typedef unsigned short u16;
typedef unsigned int u32;

constexpr float CLIPV  = 8.0f;
constexpr float LN_EPS_ = 1e-5f;
constexpr float SCALE_ = 0.08838834764831845f;   // 1/sqrt(128)
constexpr float LOG2E_ = 1.4426950408889634f;

using f32x4 = __attribute__((ext_vector_type(4))) float;
using s16x8 = __attribute__((ext_vector_type(8))) short;

__device__ inline u16 f2bf(float f) {
  union { float f; u32 u; } v; v.f = f;
  u32 r = (v.u + 0x7FFFu + ((v.u >> 16) & 1u)) >> 16;
  return (u16)r;
}
__device__ inline float bf2f(u16 u) {
  union { u32 u; float f; } v; v.u = ((u32)u) << 16;
  return v.f;
}

typedef __attribute__((address_space(1))) void gvoid;
typedef __attribute__((address_space(3))) void lvoid;
__device__ inline void gload_lds16(const void* g, void* l) {
  __builtin_amdgcn_global_load_lds((gvoid*)g, (lvoid*)l, 16, 0, 0);
}

__device__ inline f32x4 mfma16(s16x8 a, s16x8 b, f32x4 c) {
  return __builtin_amdgcn_mfma_f32_16x16x32_bf16(a, b, c, 0, 0, 0);
}

// ---------------- kernel 1: f32 -> bf16 elementwise ----------------
__global__ void k_cvt_bf16(const float* __restrict__ in, u16* __restrict__ out, int nvec) {
  int i = blockIdx.x * 256 + threadIdx.x;
  if (i >= nvec) return;
  float4 a = ((const float4*)in)[i * 2];
  float4 b = ((const float4*)in)[i * 2 + 1];
  u16 tmp[8];
  tmp[0] = f2bf(a.x); tmp[1] = f2bf(a.y); tmp[2] = f2bf(a.z); tmp[3] = f2bf(a.w);
  tmp[4] = f2bf(b.x); tmp[5] = f2bf(b.y); tmp[6] = f2bf(b.z); tmp[7] = f2bf(b.w);
  ((uint4*)out)[i] = *(const uint4*)tmp;
}

// ---------------- kernel 2: transpose + convert: src f32 [R][C] -> dst bf16 [C][R] ----------------
__global__ void k_transpose_cvt(const float* __restrict__ src, u16* __restrict__ dst, int R, int C) {
  __shared__ float tile[32][33];
  int c0 = blockIdx.x * 32, r0 = blockIdx.y * 32;
  int tx = threadIdx.x & 31, ty = threadIdx.x >> 5;   // 32 x 8
  #pragma unroll
  for (int i = 0; i < 32; i += 8)
    tile[ty + i][tx] = src[(size_t)(r0 + ty + i) * C + (c0 + tx)];
  __syncthreads();
  #pragma unroll
  for (int i = 0; i < 32; i += 8)
    dst[(size_t)(c0 + ty + i) * R + (r0 + tx)] = f2bf(tile[tx][ty + i]);
}

// ---------------- kernel 3/7: bf16 GEMM, C = A[M][K] * Bt[N][K]^T ----------------
// m97 structure: 128x128 tile, BK=32, 4 waves (2x2), 4x4 16x16x32 frags per wave.
// LDS layout kg-major subtiled: slot s = kg*128 + row holds T[row][kg*8..kg*8+8) -> conflict-free ds_read_b128.
template <int EPI>   // 0: clip to +-8, store bf16 ; 1: store f32
__global__ void k_gemm(const u16* __restrict__ A, const u16* __restrict__ Bt,
                       void* __restrict__ Cout, int M, int N, int K) {
  __shared__ u16 lA[4096];
  __shared__ u16 lB[4096];
  const int t = threadIdx.x;
  const int lane = t & 63, w = t >> 6;
  const int wm = w >> 1, wn = w & 1;
  const int lg = lane >> 4, lc = lane & 15;
  const int m0 = blockIdx.y * 128, n0 = blockIdx.x * 128;

  f32x4 acc[4][4];
  #pragma unroll
  for (int i = 0; i < 4; ++i)
    #pragma unroll
    for (int j = 0; j < 4; ++j) acc[i][j] = (f32x4){0.f, 0.f, 0.f, 0.f};

  for (int k0 = 0; k0 < K; k0 += 32) {
    #pragma unroll
    for (int it = 0; it < 2; ++it) {
      int s = it * 256 + t;            // 0..511 slots of 16B
      int row = s & 127, kg = s >> 7;
      gload_lds16(A  + (size_t)(m0 + row) * K + (k0 + kg * 8), &lA[s * 8]);
      gload_lds16(Bt + (size_t)(n0 + row) * K + (k0 + kg * 8), &lB[s * 8]);
    }
    __syncthreads();
    s16x8 af[4], bfr[4];
    #pragma unroll
    for (int i = 0; i < 4; ++i)
      af[i] = *(const s16x8*)&lA[(lg * 128 + wm * 64 + i * 16 + lc) * 8];
    #pragma unroll
    for (int j = 0; j < 4; ++j)
      bfr[j] = *(const s16x8*)&lB[(lg * 128 + wn * 64 + j * 16 + lc) * 8];
    #pragma unroll
    for (int i = 0; i < 4; ++i)
      #pragma unroll
      for (int j = 0; j < 4; ++j)
        acc[i][j] = mfma16(af[i], bfr[j], acc[i][j]);
    __syncthreads();
  }

  #pragma unroll
  for (int i = 0; i < 4; ++i)
    #pragma unroll
    for (int j = 0; j < 4; ++j)
      #pragma unroll
      for (int r = 0; r < 4; ++r) {
        int m = m0 + wm * 64 + i * 16 + lg * 4 + r;
        int n = n0 + wn * 64 + j * 16 + lc;
        float v = acc[i][j][r];
        if (EPI == 0) {
          v = fminf(fmaxf(v, -CLIPV), CLIPV);
          ((u16*)Cout)[(size_t)m * N + n] = f2bf(v);
        } else {
          ((float*)Cout)[(size_t)m * N + n] = v;
        }
      }
}

// ---------------- kernel 4: LN(q), LN(k) over D=4096 + head relayout of q,k,v ----------------
__device__ inline void unpack8(uint4 u, float* f) {
  const u16* p = (const u16*)&u;
  #pragma unroll
  for (int j = 0; j < 8; ++j) f[j] = bf2f(p[j]);
}

__global__ void k_ln_reorder(const u16* __restrict__ qkv,
                             const float* __restrict__ qw, const float* __restrict__ qb,
                             const float* __restrict__ kw, const float* __restrict__ kb,
                             u16* __restrict__ Qo, u16* __restrict__ Ko, u16* __restrict__ Vo) {
  const int row = blockIdx.x;               // 0..B*S-1
  const int b = row >> 11, s = row & 2047;
  const int t = threadIdx.x;
  const int lane = t & 63, w = t >> 6;
  const uint4* base = (const uint4*)(qkv + (size_t)row * (3 * DD));  // 1536 x uint4

  __shared__ float redsum[8], redss[8];

  uint4 q4[2], k4[2], v4[2];
  q4[0] = base[t];        q4[1] = base[256 + t];
  k4[0] = base[512 + t];  k4[1] = base[768 + t];
  v4[0] = base[1024 + t]; v4[1] = base[1280 + t];

  float qx[16], kx[16];
  unpack8(q4[0], qx); unpack8(q4[1], qx + 8);
  unpack8(k4[0], kx); unpack8(k4[1], kx + 8);

  float qs = 0.f, qss = 0.f, ks = 0.f, kss = 0.f;
  #pragma unroll
  for (int i = 0; i < 16; ++i) {
    qs += qx[i]; qss += qx[i] * qx[i];
    ks += kx[i]; kss += kx[i] * kx[i];
  }
  #pragma unroll
  for (int off = 1; off < 64; off <<= 1) {
    qs  += __shfl_xor(qs, off);  qss += __shfl_xor(qss, off);
    ks  += __shfl_xor(ks, off);  kss += __shfl_xor(kss, off);
  }
  if (lane == 0) { redsum[w] = qs; redss[w] = qss; redsum[4 + w] = ks; redss[4 + w] = kss; }
  __syncthreads();
  float qsum = redsum[0] + redsum[1] + redsum[2] + redsum[3];
  float qs2  = redss[0]  + redss[1]  + redss[2]  + redss[3];
  float ksum = redsum[4] + redsum[5] + redsum[6] + redsum[7];
  float ks2  = redss[4]  + redss[5]  + redss[6]  + redss[7];
  const float inv = 1.0f / (float)DD;
  float qmu = qsum * inv, qvar = qs2 * inv - qmu * qmu;
  float kmu = ksum * inv, kvar = ks2 * inv - kmu * kmu;
  float qrs = rsqrtf(qvar + LN_EPS_);
  float krs = rsqrtf(kvar + LN_EPS_);

  #pragma unroll
  for (int ch = 0; ch < 2; ++ch) {
    int c0 = ch * 2048 + t * 8;
    int hh = c0 >> 7, hd0 = c0 & 127;
    size_t idx = (((size_t)b * HH + hh) * SS + s) * HDD + hd0;
    // q
    {
      float4 w0 = *(const float4*)(qw + c0), w1 = *(const float4*)(qw + c0 + 4);
      float4 b0 = *(const float4*)(qb + c0), b1 = *(const float4*)(qb + c0 + 4);
      float wa[8] = {w0.x, w0.y, w0.z, w0.w, w1.x, w1.y, w1.z, w1.w};
      float ba[8] = {b0.x, b0.y, b0.z, b0.w, b1.x, b1.y, b1.z, b1.w};
      u16 tmp[8];
      #pragma unroll
      for (int j = 0; j < 8; ++j)
        tmp[j] = f2bf((qx[ch * 8 + j] - qmu) * qrs * wa[j] + ba[j]);
      *(uint4*)(Qo + idx) = *(const uint4*)tmp;
    }
    // k
    {
      float4 w0 = *(const float4*)(kw + c0), w1 = *(const float4*)(kw + c0 + 4);
      float4 b0 = *(const float4*)(kb + c0), b1 = *(const float4*)(kb + c0 + 4);
      float wa[8] = {w0.x, w0.y, w0.z, w0.w, w1.x, w1.y, w1.z, w1.w};
      float ba[8] = {b0.x, b0.y, b0.z, b0.w, b1.x, b1.y, b1.z, b1.w};
      u16 tmp[8];
      #pragma unroll
      for (int j = 0; j < 8; ++j)
        tmp[j] = f2bf((kx[ch * 8 + j] - kmu) * krs * wa[j] + ba[j]);
      *(uint4*)(Ko + idx) = *(const uint4*)tmp;
    }
    // v: raw copy (already clipped bf16)
    *(uint4*)(Vo + idx) = v4[ch];
  }
}

// ---------------- kernel 5: flash attention with ALiBi + causal ----------------
// Swapped QK^T: S^T = mfma(A=K, B=Q). 4 waves x 16 q-rows = 64-row Q tile, KV tile 64.
__global__ void k_attn(const u16* __restrict__ Qg, const u16* __restrict__ Kg,
                       const u16* __restrict__ Vg, u16* __restrict__ Og) {
  const int qt = blockIdx.x;                // q tile (64 rows)
  const int bh = blockIdx.y;                // b*H + h
  const int b = bh >> 5, h = bh & 31;
  const int t = threadIdx.x;
  const int lane = t & 63, w = t >> 6;
  const int lg = lane >> 4, lc = lane & 15;
  const float slope = exp2f(-0.25f * (float)(h + 1));

  __shared__ u16 lK[8192];                  // [64 kv][128 hd], 16B-slot XOR swizzled by (row&7)
  __shared__ u16 lV[8192];                  // V^T [128 hd][64 kv], XOR swizzled
  __shared__ u16 lP[4][1024];               // per-wave P, subtiled [kv/8][16 q][8]

  const int q0 = qt * 64 + w * 16;
  const size_t bhS = (size_t)bh * SS;

  s16x8 qf[4];
  {
    const u16* qrow = Qg + (bhS + q0 + lc) * HDD;
    #pragma unroll
    for (int kt = 0; kt < 4; ++kt) qf[kt] = *(const s16x8*)(qrow + kt * 32 + lg * 8);
  }

  f32x4 o[8];
  #pragma unroll
  for (int hf = 0; hf < 8; ++hf) o[hf] = (f32x4){0.f, 0.f, 0.f, 0.f};
  float m_r = -1e30f, l_r = 0.f;

  for (int kv0 = 0; kv0 <= qt * 64; kv0 += 64) {
    // stage K tile (pre-swizzled global source, linear LDS dest)
    #pragma unroll
    for (int it = 0; it < 4; ++it) {
      int sl = it * 256 + t;                 // 0..1023 16B slots
      int row = sl >> 4, s16i = sl & 15;
      const u16* src = Kg + (bhS + kv0 + row) * HDD + ((s16i ^ (row & 7)) * 8);
      gload_lds16(src, &lK[sl * 8]);
    }
    // stage V transposed (reg-staged, swizzled scatter)
    #pragma unroll
    for (int c = 0; c < 4; ++c) {
      int e = c * 256 + t;                   // 0..1023 8-elem vectors
      int row = e >> 4, hd0 = (e & 15) * 8;
      uint4 vv = *(const uint4*)(Vg + (bhS + kv0 + row) * HDD + hd0);
      const u16* pv = (const u16*)&vv;
      #pragma unroll
      for (int jj = 0; jj < 8; ++jj) {
        int r2 = hd0 + jj;
        lV[r2 * 64 + (((row >> 3) ^ (r2 & 7)) * 8) + (row & 7)] = pv[jj];
      }
    }
    __syncthreads();

    // QK^T (swapped): lane holds S^T(kv = i*16 + lg*4 + r, q = lc)
    f32x4 st[4];
    #pragma unroll
    for (int i = 0; i < 4; ++i) {
      st[i] = (f32x4){0.f, 0.f, 0.f, 0.f};
      #pragma unroll
      for (int kt = 0; kt < 4; ++kt) {
        int r = i * 16 + lc;
        const s16x8 ka = *(const s16x8*)&lK[r * 128 + (((kt * 4 + lg) ^ (r & 7)) * 8)];
        st[i] = mfma16(ka, qf[kt], st[i]);
      }
    }

    // scores + ALiBi + causal mask
    float sc[4][4];
    float pm = -1e30f;
    const int qg = q0 + lc;
    #pragma unroll
    for (int i = 0; i < 4; ++i)
      #pragma unroll
      for (int r = 0; r < 4; ++r) {
        int kv = kv0 + i * 16 + lg * 4 + r;
        float x = (kv <= qg) ? st[i][r] * SCALE_ - slope * (float)(qg - kv) : -1e30f;
        sc[i][r] = x;
        pm = fmaxf(pm, x);
      }
    pm = fmaxf(pm, __shfl_xor(pm, 16));
    pm = fmaxf(pm, __shfl_xor(pm, 32));
    float m_new = fmaxf(m_r, pm);
    float alpha = exp2f((m_r - m_new) * LOG2E_);
    float rsum = 0.f;
    #pragma unroll
    for (int i = 0; i < 4; ++i)
      #pragma unroll
      for (int r = 0; r < 4; ++r) {
        float p = exp2f((sc[i][r] - m_new) * LOG2E_);
        rsum += p;
        int kv = i * 16 + lg * 4 + r;
        lP[w][(kv >> 3) * 128 + lc * 8 + (kv & 7)] = f2bf(p);
      }
    rsum += __shfl_xor(rsum, 16);
    rsum += __shfl_xor(rsum, 32);
    l_r = l_r * alpha + rsum;
    m_r = m_new;

    // rescale O (O rows are q = lg*4 + r -> need alpha from lane (lg*4+r))
    float al[4];
    #pragma unroll
    for (int r = 0; r < 4; ++r) al[r] = __shfl(alpha, lg * 4 + r);
    #pragma unroll
    for (int hf = 0; hf < 8; ++hf) {
      o[hf][0] *= al[0]; o[hf][1] *= al[1]; o[hf][2] *= al[2]; o[hf][3] *= al[3];
    }

    // PV: O[q][hd] += P[q][kv] * V[kv][hd]
    #pragma unroll
    for (int kt = 0; kt < 2; ++kt) {
      const s16x8 pa = *(const s16x8*)&lP[w][(kt * 4 + lg) * 128 + lc * 8];
      #pragma unroll
      for (int hf = 0; hf < 8; ++hf) {
        int r2 = hf * 16 + lc;
        const s16x8 vb = *(const s16x8*)&lV[r2 * 64 + (((kt * 4 + lg) ^ (r2 & 7)) * 8)];
        o[hf] = mfma16(pa, vb, o[hf]);
      }
    }
    __syncthreads();
  }

  // epilogue: normalize by l, store to [B][S][D] bf16
  float linv[4];
  #pragma unroll
  for (int r = 0; r < 4; ++r) linv[r] = 1.f / __shfl(l_r, lg * 4 + r);
  #pragma unroll
  for (int hf = 0; hf < 8; ++hf)
    #pragma unroll
    for (int r = 0; r < 4; ++r) {
      size_t idx = ((size_t)b * SS + (q0 + lg * 4 + r)) * DD + h * HDD + hf * 16 + lc;
      Og[idx] = f2bf(o[hf][r] * linv[r]);
    }
}

// ---------------- launch ----------------
extern "C" void kernel_launch(void* const* d_in, const int* in_sizes, int n_in,
                              void* d_out, int out_size, void* d_ws, size_t ws_size,
                              hipStream_t stream) {
  const float* hidden = (const float*)d_in[0];
  const float* Wqkv   = (const float*)d_in[1];
  const float* Wout   = (const float*)d_in[2];
  const float* qw     = (const float*)d_in[3];
  const float* qb     = (const float*)d_in[4];
  const float* kw     = (const float*)d_in[5];
  const float* kb     = (const float*)d_in[6];
  float* out = (float*)d_out;
  char* ws = (char*)d_ws;

  // workspace layout (total 256 MB)
  u16* Xb    = (u16*)(ws);                    // 33,554,432 B  (later reused as attn_out)
  u16* WqkvT = (u16*)(ws + 33554432);         // 100,663,296 B (later reused as Q,K,V)
  u16* Qb    = (u16*)(ws + 33554432);
  u16* Kb    = (u16*)(ws + 67108864);
  u16* Vb    = (u16*)(ws + 100663296);
  u16* WoutT = (u16*)(ws + 134217728);        // 33,554,432 B
  u16* qkv   = (u16*)(ws + 167772160);        // 100,663,296 B
  u16* attnO = Xb;

  k_cvt_bf16<<<8192, 256, 0, stream>>>(hidden, Xb, 2097152);
  k_transpose_cvt<<<dim3(12288 / 32, 4096 / 32), 256, 0, stream>>>(Wqkv, WqkvT, 4096, 12288);
  k_transpose_cvt<<<dim3(4096 / 32, 4096 / 32), 256, 0, stream>>>(Wout, WoutT, 4096, 4096);
  k_gemm<0><<<dim3(96, 32), 256, 0, stream>>>(Xb, WqkvT, qkv, 4096, 12288, 4096);
  k_ln_reorder<<<4096, 256, 0, stream>>>(qkv, qw, qb, kw, kb, Qb, Kb, Vb);
  k_attn<<<dim3(32, 64), 256, 0, stream>>>(Qb, Kb, Vb, attnO);
  k_gemm<1><<<dim3(32, 32), 256, 0, stream>>>(attnO, WoutT, out, 4096, 4096, 4096);
}

// Round 2
// 1388.019 us; speedup vs baseline: 1.4211x; 1.4211x over previous
//
#include <hip/hip_runtime.h>
#include <hip/hip_bf16.h>
#include <stdint.h>

// Problem constants
#define BB 2
#define SS 2048
#define DD 4096
#define HH 32
#define HDD 128

typedef unsigned short u16;
typedef unsigned int u32;

constexpr float CLIPV  = 8.0f;
constexpr float LN_EPS_ = 1e-5f;
constexpr float SCALE_ = 0.08838834764831845f;   // 1/sqrt(128)
constexpr float LOG2E_ = 1.4426950408889634f;

using f32x4 = __attribute__((ext_vector_type(4))) float;
using s16x8 = __attribute__((ext_vector_type(8))) short;

__device__ inline u16 f2bf(float f) {
  union { float f; u32 u; } v; v.f = f;
  u32 r = (v.u + 0x7FFFu + ((v.u >> 16) & 1u)) >> 16;
  return (u16)r;
}
__device__ inline float bf2f(u16 u) {
  union { u32 u; float f; } v; v.u = ((u32)u) << 16;
  return v.f;
}

typedef __attribute__((address_space(1))) void gvoid;
typedef __attribute__((address_space(3))) void lvoid;
__device__ inline void gload_lds16(const void* g, void* l) {
  __builtin_amdgcn_global_load_lds((gvoid*)g, (lvoid*)l, 16, 0, 0);
}

__device__ inline f32x4 mfma16(s16x8 a, s16x8 b, f32x4 c) {
  return __builtin_amdgcn_mfma_f32_16x16x32_bf16(a, b, c, 0, 0, 0);
}

// ---------------- kernel 1: f32 -> bf16 elementwise ----------------
__global__ void k_cvt_bf16(const float* __restrict__ in, u16* __restrict__ out, int nvec) {
  int i = blockIdx.x * 256 + threadIdx.x;
  if (i >= nvec) return;
  float4 a = ((const float4*)in)[i * 2];
  float4 b = ((const float4*)in)[i * 2 + 1];
  u16 tmp[8];
  tmp[0] = f2bf(a.x); tmp[1] = f2bf(a.y); tmp[2] = f2bf(a.z); tmp[3] = f2bf(a.w);
  tmp[4] = f2bf(b.x); tmp[5] = f2bf(b.y); tmp[6] = f2bf(b.z); tmp[7] = f2bf(b.w);
  ((uint4*)out)[i] = *(const uint4*)tmp;
}

// ---------------- kernel 2: transpose + convert: src f32 [R][C] -> dst bf16 [C][R] ----------------
__global__ void k_transpose_cvt(const float* __restrict__ src, u16* __restrict__ dst, int R, int C) {
  __shared__ float tile[32][33];
  int c0 = blockIdx.x * 32, r0 = blockIdx.y * 32;
  int tx = threadIdx.x & 31, ty = threadIdx.x >> 5;   // 32 x 8
  #pragma unroll
  for (int i = 0; i < 32; i += 8)
    tile[ty + i][tx] = src[(size_t)(r0 + ty + i) * C + (c0 + tx)];
  __syncthreads();
  #pragma unroll
  for (int i = 0; i < 32; i += 8)
    dst[(size_t)(c0 + ty + i) * R + (r0 + tx)] = f2bf(tile[tx][ty + i]);
}

// ---------------- 256x256 8-phase GEMM: C = A[M][K] * Bt[N][K]^T ----------------
// 8 waves (2M x 4N), BK=64, 128KiB LDS (2 dbuf x 2 halves x 128x64 bf16 x {A,B}).
// LDS XOR swizzle: 16B slot ^= (row&7), applied on the pre-swizzled GLOBAL source
// (global_load_lds dest must be linear) and on the ds_read addresses.
// Staging schedule per K-tile t (phases p1..p4), verified race-free given the
// per-phase lgkmcnt(0) drains:
//   p1: read B[j0,j1]+A[mh0] (12 b128); stage A1(t+1) -> buf d^1
//   p2: read B[j2,j3] (4 b128)
//   p3: read A[mh1] (8 b128); stage B0,B1(t+2) -> buf d (B reads drained @p2)
//   p4: stage A0(t+2) -> buf d (A reads drained @p3); vmcnt(6) [epilogue: 0]
// In-flight invariant at tile start: {B0,B1,A0}(t+1) = 6 loads -> vmcnt(6).
__device__ __forceinline__ void stage_half(u16* ldsHalf, const u16* g, int K, int tid) {
  #pragma unroll
  for (int it = 0; it < 2; ++it) {
    int p = (it << 9) + tid;           // 16B slot index 0..1023
    int row = p >> 3;                  // 0..127
    int slotk = (p & 7) ^ (row & 7);   // inverse-swizzled source slot
    gload_lds16(g + (size_t)row * K + (slotk << 3), ldsHalf + ((size_t)p << 3));
  }
}

#define MFMA_QUAD(MB, JB)                                                     \
  _Pragma("unroll")                                                           \
  for (int i_ = 0; i_ < 4; ++i_) {                                            \
    _Pragma("unroll")                                                         \
    for (int jj_ = 0; jj_ < 2; ++jj_) {                                       \
      acc[(MB) + i_][(JB) + jj_] =                                            \
          mfma16(aF[i_][0], bF[(JB) + jj_][0], acc[(MB) + i_][(JB) + jj_]);   \
      acc[(MB) + i_][(JB) + jj_] =                                            \
          mfma16(aF[i_][1], bF[(JB) + jj_][1], acc[(MB) + i_][(JB) + jj_]);   \
    }                                                                         \
  }

template <int EPI>   // 0: clip to +-8, store bf16 ; 1: store f32
__launch_bounds__(512)
__global__ void k_gemm256(const u16* __restrict__ A, const u16* __restrict__ Bt,
                          void* __restrict__ Cout, int M, int N, int K, int nBX) {
  __shared__ u16 sA[32768];   // 2 bufs x 2 halves x 128x64
  __shared__ u16 sB[32768];
  const int tid = threadIdx.x;
  const int lane = tid & 63, w = tid >> 6;
  const int wm = w >> 2, wn = w & 3;          // 2 x 4 waves
  const int lg = lane >> 4, lc = lane & 15;

  // bijective XCD swizzle (nwg divisible by 8 for all our launches)
  const int nwg = gridDim.x;
  const int cpx = nwg >> 3;
  const int id2 = (blockIdx.x & 7) * cpx + (blockIdx.x >> 3);
  const int bx = id2 % nBX, by = id2 / nBX;
  const int m0 = by * 256, n0 = bx * 256;

  const int NT = K >> 6;
  const u16* gA = A  + (size_t)m0 * K;
  const u16* gB = Bt + (size_t)n0 * K;

  // swizzled k-slot terms for reads (u16 units)
  const int xt0 = ((lg) ^ (lc & 7)) * 8;
  const int xt1 = xt0 ^ 32;
  const int rowoff = lc * 64;

  f32x4 acc[8][4];
  #pragma unroll
  for (int i = 0; i < 8; ++i)
    #pragma unroll
    for (int j = 0; j < 4; ++j) acc[i][j] = (f32x4){0.f, 0.f, 0.f, 0.f};

  // ---- prologue: tile0 fully + {B0,B1,A0}(tile1) ----
  stage_half(sA,        gA,                    K, tid);
  stage_half(sA + 8192, gA + (size_t)128 * K,  K, tid);
  stage_half(sB,        gB,                    K, tid);
  stage_half(sB + 8192, gB + (size_t)128 * K,  K, tid);
  if (NT > 1) {
    stage_half(sB + 16384,        gB + 64,                   K, tid);
    stage_half(sB + 16384 + 8192, gB + (size_t)128 * K + 64, K, tid);
    stage_half(sA + 16384,        gA + 64,                   K, tid);
    asm volatile("s_waitcnt vmcnt(6)" ::: "memory");
  } else {
    asm volatile("s_waitcnt vmcnt(0)" ::: "memory");
  }
  __builtin_amdgcn_s_barrier();

  for (int t = 0; t < NT; ++t) {
    const int d = t & 1;
    u16* aB = sA + d * 16384 + wm * 8192;
    u16* bB = sB + d * 16384 + (wn >> 1) * 8192 + (wn & 1) * 4096;

    s16x8 aF[4][2], bF[4][2];

    // ---------- phase 1: quad (mh0, nh0) ----------
    #pragma unroll
    for (int j = 0; j < 2; ++j) {
      bF[j][0] = *(const s16x8*)(bB + j * 1024 + rowoff + xt0);
      bF[j][1] = *(const s16x8*)(bB + j * 1024 + rowoff + xt1);
    }
    #pragma unroll
    for (int i = 0; i < 4; ++i) {
      aF[i][0] = *(const s16x8*)(aB + i * 1024 + rowoff + xt0);
      aF[i][1] = *(const s16x8*)(aB + i * 1024 + rowoff + xt1);
    }
    if (t + 1 < NT)
      stage_half(sA + (d ^ 1) * 16384 + 8192,
                 gA + (size_t)128 * K + (size_t)(t + 1) * 64, K, tid);
    __builtin_amdgcn_s_barrier();
    asm volatile("s_waitcnt lgkmcnt(0)" ::: "memory");
    __builtin_amdgcn_s_setprio(1);
    MFMA_QUAD(0, 0)
    __builtin_amdgcn_s_setprio(0);
    __builtin_amdgcn_s_barrier();

    // ---------- phase 2: quad (mh0, nh1) ----------
    #pragma unroll
    for (int j = 2; j < 4; ++j) {
      bF[j][0] = *(const s16x8*)(bB + j * 1024 + rowoff + xt0);
      bF[j][1] = *(const s16x8*)(bB + j * 1024 + rowoff + xt1);
    }
    __builtin_amdgcn_s_barrier();
    asm volatile("s_waitcnt lgkmcnt(0)" ::: "memory");
    __builtin_amdgcn_s_setprio(1);
    MFMA_QUAD(0, 2)
    __builtin_amdgcn_s_setprio(0);
    __builtin_amdgcn_s_barrier();

    // ---------- phase 3: quad (mh1, nh0) ----------
    #pragma unroll
    for (int i = 0; i < 4; ++i) {
      aF[i][0] = *(const s16x8*)(aB + 4096 + i * 1024 + rowoff + xt0);
      aF[i][1] = *(const s16x8*)(aB + 4096 + i * 1024 + rowoff + xt1);
    }
    if (t + 2 < NT) {
      stage_half(sB + d * 16384,        gB + (size_t)(t + 2) * 64,                   K, tid);
      stage_half(sB + d * 16384 + 8192, gB + (size_t)128 * K + (size_t)(t + 2) * 64, K, tid);
    }
    __builtin_amdgcn_s_barrier();
    asm volatile("s_waitcnt lgkmcnt(0)" ::: "memory");
    __builtin_amdgcn_s_setprio(1);
    MFMA_QUAD(4, 0)
    __builtin_amdgcn_s_setprio(0);
    __builtin_amdgcn_s_barrier();

    // ---------- phase 4: quad (mh1, nh1) ----------
    if (t + 2 < NT)
      stage_half(sA + d * 16384, gA + (size_t)(t + 2) * 64, K, tid);
    __builtin_amdgcn_s_barrier();
    asm volatile("s_waitcnt lgkmcnt(0)" ::: "memory");
    __builtin_amdgcn_s_setprio(1);
    MFMA_QUAD(4, 2)
    __builtin_amdgcn_s_setprio(0);
    if (t + 2 < NT) asm volatile("s_waitcnt vmcnt(6)" ::: "memory");
    else            asm volatile("s_waitcnt vmcnt(0)" ::: "memory");
    __builtin_amdgcn_s_barrier();
  }

  // ---- epilogue ----
  #pragma unroll
  for (int i = 0; i < 8; ++i)
    #pragma unroll
    for (int j = 0; j < 4; ++j)
      #pragma unroll
      for (int r = 0; r < 4; ++r) {
        int m = m0 + wm * 128 + i * 16 + lg * 4 + r;
        int n = n0 + wn * 64 + j * 16 + lc;
        float v = acc[i][j][r];
        if (EPI == 0) {
          v = fminf(fmaxf(v, -CLIPV), CLIPV);
          ((u16*)Cout)[(size_t)m * N + n] = f2bf(v);
        } else {
          ((float*)Cout)[(size_t)m * N + n] = v;
        }
      }
}

// ---------------- kernel 4: LN(q), LN(k) over D=4096 + head relayout of q,k,v ----------------
__device__ inline void unpack8(uint4 u, float* f) {
  const u16* p = (const u16*)&u;
  #pragma unroll
  for (int j = 0; j < 8; ++j) f[j] = bf2f(p[j]);
}

__global__ void k_ln_reorder(const u16* __restrict__ qkv,
                             const float* __restrict__ qw, const float* __restrict__ qb,
                             const float* __restrict__ kw, const float* __restrict__ kb,
                             u16* __restrict__ Qo, u16* __restrict__ Ko, u16* __restrict__ Vo) {
  const int row = blockIdx.x;               // 0..B*S-1
  const int b = row >> 11, s = row & 2047;
  const int t = threadIdx.x;
  const int lane = t & 63, w = t >> 6;
  const uint4* base = (const uint4*)(qkv + (size_t)row * (3 * DD));  // 1536 x uint4

  __shared__ float redsum[8], redss[8];

  uint4 q4[2], k4[2], v4[2];
  q4[0] = base[t];        q4[1] = base[256 + t];
  k4[0] = base[512 + t];  k4[1] = base[768 + t];
  v4[0] = base[1024 + t]; v4[1] = base[1280 + t];

  float qx[16], kx[16];
  unpack8(q4[0], qx); unpack8(q4[1], qx + 8);
  unpack8(k4[0], kx); unpack8(k4[1], kx + 8);

  float qs = 0.f, qss = 0.f, ks = 0.f, kss = 0.f;
  #pragma unroll
  for (int i = 0; i < 16; ++i) {
    qs += qx[i]; qss += qx[i] * qx[i];
    ks += kx[i]; kss += kx[i] * kx[i];
  }
  #pragma unroll
  for (int off = 1; off < 64; off <<= 1) {
    qs  += __shfl_xor(qs, off);  qss += __shfl_xor(qss, off);
    ks  += __shfl_xor(ks, off);  kss += __shfl_xor(kss, off);
  }
  if (lane == 0) { redsum[w] = qs; redss[w] = qss; redsum[4 + w] = ks; redss[4 + w] = kss; }
  __syncthreads();
  float qsum = redsum[0] + redsum[1] + redsum[2] + redsum[3];
  float qs2  = redss[0]  + redss[1]  + redss[2]  + redss[3];
  float ksum = redsum[4] + redsum[5] + redsum[6] + redsum[7];
  float ks2  = redss[4]  + redss[5]  + redss[6]  + redss[7];
  const float inv = 1.0f / (float)DD;
  float qmu = qsum * inv, qvar = qs2 * inv - qmu * qmu;
  float kmu = ksum * inv, kvar = ks2 * inv - kmu * kmu;
  float qrs = rsqrtf(qvar + LN_EPS_);
  float krs = rsqrtf(kvar + LN_EPS_);

  #pragma unroll
  for (int ch = 0; ch < 2; ++ch) {
    int c0 = ch * 2048 + t * 8;
    int hh = c0 >> 7, hd0 = c0 & 127;
    size_t idx = (((size_t)b * HH + hh) * SS + s) * HDD + hd0;
    // q
    {
      float4 w0 = *(const float4*)(qw + c0), w1 = *(const float4*)(qw + c0 + 4);
      float4 b0 = *(const float4*)(qb + c0), b1 = *(const float4*)(qb + c0 + 4);
      float wa[8] = {w0.x, w0.y, w0.z, w0.w, w1.x, w1.y, w1.z, w1.w};
      float ba[8] = {b0.x, b0.y, b0.z, b0.w, b1.x, b1.y, b1.z, b1.w};
      u16 tmp[8];
      #pragma unroll
      for (int j = 0; j < 8; ++j)
        tmp[j] = f2bf((qx[ch * 8 + j] - qmu) * qrs * wa[j] + ba[j]);
      *(uint4*)(Qo + idx) = *(const uint4*)tmp;
    }
    // k
    {
      float4 w0 = *(const float4*)(kw + c0), w1 = *(const float4*)(kw + c0 + 4);
      float4 b0 = *(const float4*)(kb + c0), b1 = *(const float4*)(kb + c0 + 4);
      float wa[8] = {w0.x, w0.y, w0.z, w0.w, w1.x, w1.y, w1.z, w1.w};
      float ba[8] = {b0.x, b0.y, b0.z, b0.w, b1.x, b1.y, b1.z, b1.w};
      u16 tmp[8];
      #pragma unroll
      for (int j = 0; j < 8; ++j)
        tmp[j] = f2bf((kx[ch * 8 + j] - kmu) * krs * wa[j] + ba[j]);
      *(uint4*)(Ko + idx) = *(const uint4*)tmp;
    }
    // v: raw copy (already clipped bf16)
    *(uint4*)(Vo + idx) = v4[ch];
  }
}

// ---------------- kernel 5: flash attention with ALiBi + causal ----------------
// Swapped QK^T: S^T = mfma(A=K, B=Q). 4 waves x 16 q-rows = 64-row Q tile, KV tile 64.
__global__ void k_attn(const u16* __restrict__ Qg, const u16* __restrict__ Kg,
                       const u16* __restrict__ Vg, u16* __restrict__ Og) {
  const int qt = blockIdx.x;                // q tile (64 rows)
  const int bh = blockIdx.y;                // b*H + h
  const int b = bh >> 5, h = bh & 31;
  const int t = threadIdx.x;
  const int lane = t & 63, w = t >> 6;
  const int lg = lane >> 4, lc = lane & 15;
  const float slope = exp2f(-0.25f * (float)(h + 1));

  __shared__ u16 lK[8192];                  // [64 kv][128 hd], 16B-slot XOR swizzled by (row&7)
  __shared__ u16 lV[8192];                  // V^T [128 hd][64 kv], XOR swizzled
  __shared__ u16 lP[4][1024];               // per-wave P, subtiled [kv/8][16 q][8]

  const int q0 = qt * 64 + w * 16;
  const size_t bhS = (size_t)bh * SS;

  s16x8 qf[4];
  {
    const u16* qrow = Qg + (bhS + q0 + lc) * HDD;
    #pragma unroll
    for (int kt = 0; kt < 4; ++kt) qf[kt] = *(const s16x8*)(qrow + kt * 32 + lg * 8);
  }

  f32x4 o[8];
  #pragma unroll
  for (int hf = 0; hf < 8; ++hf) o[hf] = (f32x4){0.f, 0.f, 0.f, 0.f};
  float m_r = -1e30f, l_r = 0.f;

  for (int kv0 = 0; kv0 <= qt * 64; kv0 += 64) {
    // stage K tile (pre-swizzled global source, linear LDS dest)
    #pragma unroll
    for (int it = 0; it < 4; ++it) {
      int sl = it * 256 + t;                 // 0..1023 16B slots
      int row = sl >> 4, s16i = sl & 15;
      const u16* src = Kg + (bhS + kv0 + row) * HDD + ((s16i ^ (row & 7)) * 8);
      gload_lds16(src, &lK[sl * 8]);
    }
    // stage V transposed (reg-staged, swizzled scatter)
    #pragma unroll
    for (int c = 0; c < 4; ++c) {
      int e = c * 256 + t;                   // 0..1023 8-elem vectors
      int row = e >> 4, hd0 = (e & 15) * 8;
      uint4 vv = *(const uint4*)(Vg + (bhS + kv0 + row) * HDD + hd0);
      const u16* pv = (const u16*)&vv;
      #pragma unroll
      for (int jj = 0; jj < 8; ++jj) {
        int r2 = hd0 + jj;
        lV[r2 * 64 + (((row >> 3) ^ (r2 & 7)) * 8) + (row & 7)] = pv[jj];
      }
    }
    __syncthreads();

    // QK^T (swapped): lane holds S^T(kv = i*16 + lg*4 + r, q = lc)
    f32x4 st[4];
    #pragma unroll
    for (int i = 0; i < 4; ++i) {
      st[i] = (f32x4){0.f, 0.f, 0.f, 0.f};
      #pragma unroll
      for (int kt = 0; kt < 4; ++kt) {
        int r = i * 16 + lc;
        const s16x8 ka = *(const s16x8*)&lK[r * 128 + (((kt * 4 + lg) ^ (r & 7)) * 8)];
        st[i] = mfma16(ka, qf[kt], st[i]);
      }
    }

    // scores + ALiBi + causal mask
    float sc[4][4];
    float pm = -1e30f;
    const int qg = q0 + lc;
    #pragma unroll
    for (int i = 0; i < 4; ++i)
      #pragma unroll
      for (int r = 0; r < 4; ++r) {
        int kv = kv0 + i * 16 + lg * 4 + r;
        float x = (kv <= qg) ? st[i][r] * SCALE_ - slope * (float)(qg - kv) : -1e30f;
        sc[i][r] = x;
        pm = fmaxf(pm, x);
      }
    pm = fmaxf(pm, __shfl_xor(pm, 16));
    pm = fmaxf(pm, __shfl_xor(pm, 32));
    float m_new = fmaxf(m_r, pm);
    float alpha = exp2f((m_r - m_new) * LOG2E_);
    float rsum = 0.f;
    #pragma unroll
    for (int i = 0; i < 4; ++i)
      #pragma unroll
      for (int r = 0; r < 4; ++r) {
        float p = exp2f((sc[i][r] - m_new) * LOG2E_);
        rsum += p;
        int kv = i * 16 + lg * 4 + r;
        lP[w][(kv >> 3) * 128 + lc * 8 + (kv & 7)] = f2bf(p);
      }
    rsum += __shfl_xor(rsum, 16);
    rsum += __shfl_xor(rsum, 32);
    l_r = l_r * alpha + rsum;
    m_r = m_new;

    // rescale O (O rows are q = lg*4 + r -> need alpha from lane (lg*4+r))
    float al[4];
    #pragma unroll
    for (int r = 0; r < 4; ++r) al[r] = __shfl(alpha, lg * 4 + r);
    #pragma unroll
    for (int hf = 0; hf < 8; ++hf) {
      o[hf][0] *= al[0]; o[hf][1] *= al[1]; o[hf][2] *= al[2]; o[hf][3] *= al[3];
    }

    // PV: O[q][hd] += P[q][kv] * V[kv][hd]
    #pragma unroll
    for (int kt = 0; kt < 2; ++kt) {
      const s16x8 pa = *(const s16x8*)&lP[w][(kt * 4 + lg) * 128 + lc * 8];
      #pragma unroll
      for (int hf = 0; hf < 8; ++hf) {
        int r2 = hf * 16 + lc;
        const s16x8 vb = *(const s16x8*)&lV[r2 * 64 + (((kt * 4 + lg) ^ (r2 & 7)) * 8)];
        o[hf] = mfma16(pa, vb, o[hf]);
      }
    }
    __syncthreads();
  }

  // epilogue: normalize by l, store to [B][S][D] bf16
  float linv[4];
  #pragma unroll
  for (int r = 0; r < 4; ++r) linv[r] = 1.f / __shfl(l_r, lg * 4 + r);
  #pragma unroll
  for (int hf = 0; hf < 8; ++hf)
    #pragma unroll
    for (int r = 0; r < 4; ++r) {
      size_t idx = ((size_t)b * SS + (q0 + lg * 4 + r)) * DD + h * HDD + hf * 16 + lc;
      Og[idx] = f2bf(o[hf][r] * linv[r]);
    }
}

// ---------------- launch ----------------
extern "C" void kernel_launch(void* const* d_in, const int* in_sizes, int n_in,
                              void* d_out, int out_size, void* d_ws, size_t ws_size,
                              hipStream_t stream) {
  const float* hidden = (const float*)d_in[0];
  const float* Wqkv   = (const float*)d_in[1];
  const float* Wout   = (const float*)d_in[2];
  const float* qw     = (const float*)d_in[3];
  const float* qb     = (const float*)d_in[4];
  const float* kw     = (const float*)d_in[5];
  const float* kb     = (const float*)d_in[6];
  float* out = (float*)d_out;
  char* ws = (char*)d_ws;

  // workspace layout (total 256 MB)
  u16* Xb    = (u16*)(ws);                    // 33,554,432 B  (later reused as attn_out)
  u16* WqkvT = (u16*)(ws + 33554432);         // 100,663,296 B (later reused as Q,K,V)
  u16* Qb    = (u16*)(ws + 33554432);
  u16* Kb    = (u16*)(ws + 67108864);
  u16* Vb    = (u16*)(ws + 100663296);
  u16* WoutT = (u16*)(ws + 134217728);        // 33,554,432 B
  u16* qkv   = (u16*)(ws + 167772160);        // 100,663,296 B
  u16* attnO = Xb;

  k_cvt_bf16<<<8192, 256, 0, stream>>>(hidden, Xb, 2097152);
  k_transpose_cvt<<<dim3(12288 / 32, 4096 / 32), 256, 0, stream>>>(Wqkv, WqkvT, 4096, 12288);
  k_transpose_cvt<<<dim3(4096 / 32, 4096 / 32), 256, 0, stream>>>(Wout, WoutT, 4096, 4096);
  // QKV GEMM: M=4096, N=12288, K=4096 -> 16 x 48 = 768 blocks (div by 8 ok)
  k_gemm256<0><<<768, 512, 0, stream>>>(Xb, WqkvT, qkv, 4096, 12288, 4096, 48);
  k_ln_reorder<<<4096, 256, 0, stream>>>(qkv, qw, qb, kw, kb, Qb, Kb, Vb);
  k_attn<<<dim3(32, 64), 256, 0, stream>>>(Qb, Kb, Vb, attnO);
  // out-proj GEMM: M=4096, N=4096, K=4096 -> 16 x 16 = 256 blocks
  k_gemm256<1><<<256, 512, 0, stream>>>(attnO, WoutT, out, 4096, 4096, 4096, 16);
}

// Round 3
// 934.729 us; speedup vs baseline: 2.1102x; 1.4849x over previous
//
#include <hip/hip_runtime.h>
#include <hip/hip_bf16.h>
#include <stdint.h>

// Problem constants
#define BB 2
#define SS 2048
#define DD 4096
#define HH 32
#define HDD 128

typedef unsigned short u16;
typedef unsigned int u32;

constexpr float CLIPV  = 8.0f;
constexpr float LN_EPS_ = 1e-5f;
constexpr float SCALE_ = 0.08838834764831845f;   // 1/sqrt(128)
constexpr float LOG2E_ = 1.4426950408889634f;

using f32x4 = __attribute__((ext_vector_type(4))) float;
using s16x8 = __attribute__((ext_vector_type(8))) short;

__device__ inline u16 f2bf(float f) {
  union { float f; u32 u; } v; v.f = f;
  u32 r = (v.u + 0x7FFFu + ((v.u >> 16) & 1u)) >> 16;
  return (u16)r;
}
__device__ inline float bf2f(u16 u) {
  union { u32 u; float f; } v; v.u = ((u32)u) << 16;
  return v.f;
}

typedef __attribute__((address_space(1))) void gvoid;
typedef __attribute__((address_space(3))) void lvoid;
__device__ inline void gload_lds16(const void* g, void* l) {
  __builtin_amdgcn_global_load_lds((gvoid*)g, (lvoid*)l, 16, 0, 0);
}

__device__ inline f32x4 mfma16(s16x8 a, s16x8 b, f32x4 c) {
  return __builtin_amdgcn_mfma_f32_16x16x32_bf16(a, b, c, 0, 0, 0);
}

// ---------------- kernel 1: f32 -> bf16 elementwise ----------------
__global__ void k_cvt_bf16(const float* __restrict__ in, u16* __restrict__ out, int nvec) {
  int i = blockIdx.x * 256 + threadIdx.x;
  if (i >= nvec) return;
  float4 a = ((const float4*)in)[i * 2];
  float4 b = ((const float4*)in)[i * 2 + 1];
  u16 tmp[8];
  tmp[0] = f2bf(a.x); tmp[1] = f2bf(a.y); tmp[2] = f2bf(a.z); tmp[3] = f2bf(a.w);
  tmp[4] = f2bf(b.x); tmp[5] = f2bf(b.y); tmp[6] = f2bf(b.z); tmp[7] = f2bf(b.w);
  ((uint4*)out)[i] = *(const uint4*)tmp;
}

// ---------------- kernel 2: transpose + convert: src f32 [R][C] -> dst bf16 [C][R] ----------------
__global__ void k_transpose_cvt(const float* __restrict__ src, u16* __restrict__ dst, int R, int C) {
  __shared__ float tile[32][33];
  int c0 = blockIdx.x * 32, r0 = blockIdx.y * 32;
  int tx = threadIdx.x & 31, ty = threadIdx.x >> 5;   // 32 x 8
  #pragma unroll
  for (int i = 0; i < 32; i += 8)
    tile[ty + i][tx] = src[(size_t)(r0 + ty + i) * C + (c0 + tx)];
  __syncthreads();
  #pragma unroll
  for (int i = 0; i < 32; i += 8)
    dst[(size_t)(c0 + ty + i) * R + (r0 + tx)] = f2bf(tile[tx][ty + i]);
}

// ---------------- 256x256 8-phase GEMM: C = A[M][K] * Bt[N][K]^T ----------------
__device__ __forceinline__ void stage_half(u16* ldsHalf, const u16* g, int K, int tid) {
  #pragma unroll
  for (int it = 0; it < 2; ++it) {
    int p = (it << 9) + tid;           // 16B slot index 0..1023
    int row = p >> 3;                  // 0..127
    int slotk = (p & 7) ^ (row & 7);   // inverse-swizzled source slot
    gload_lds16(g + (size_t)row * K + (slotk << 3), ldsHalf + ((size_t)p << 3));
  }
}

#define MFMA_QUAD(MB, JB)                                                     \
  _Pragma("unroll")                                                           \
  for (int i_ = 0; i_ < 4; ++i_) {                                            \
    _Pragma("unroll")                                                         \
    for (int jj_ = 0; jj_ < 2; ++jj_) {                                       \
      acc[(MB) + i_][(JB) + jj_] =                                            \
          mfma16(aF[i_][0], bF[(JB) + jj_][0], acc[(MB) + i_][(JB) + jj_]);   \
      acc[(MB) + i_][(JB) + jj_] =                                            \
          mfma16(aF[i_][1], bF[(JB) + jj_][1], acc[(MB) + i_][(JB) + jj_]);   \
    }                                                                         \
  }

template <int EPI>   // 0: clip to +-8, store bf16 ; 1: store f32
__launch_bounds__(512)
__global__ void k_gemm256(const u16* __restrict__ A, const u16* __restrict__ Bt,
                          void* __restrict__ Cout, int M, int N, int K, int nBX) {
  __shared__ u16 sA[32768];   // 2 bufs x 2 halves x 128x64
  __shared__ u16 sB[32768];
  const int tid = threadIdx.x;
  const int lane = tid & 63, w = tid >> 6;
  const int wm = w >> 2, wn = w & 3;          // 2 x 4 waves
  const int lg = lane >> 4, lc = lane & 15;

  const int nwg = gridDim.x;
  const int cpx = nwg >> 3;
  const int id2 = (blockIdx.x & 7) * cpx + (blockIdx.x >> 3);
  const int bx = id2 % nBX, by = id2 / nBX;
  const int m0 = by * 256, n0 = bx * 256;

  const int NT = K >> 6;
  const u16* gA = A  + (size_t)m0 * K;
  const u16* gB = Bt + (size_t)n0 * K;

  const int xt0 = ((lg) ^ (lc & 7)) * 8;
  const int xt1 = xt0 ^ 32;
  const int rowoff = lc * 64;

  f32x4 acc[8][4];
  #pragma unroll
  for (int i = 0; i < 8; ++i)
    #pragma unroll
    for (int j = 0; j < 4; ++j) acc[i][j] = (f32x4){0.f, 0.f, 0.f, 0.f};

  stage_half(sA,        gA,                    K, tid);
  stage_half(sA + 8192, gA + (size_t)128 * K,  K, tid);
  stage_half(sB,        gB,                    K, tid);
  stage_half(sB + 8192, gB + (size_t)128 * K,  K, tid);
  if (NT > 1) {
    stage_half(sB + 16384,        gB + 64,                   K, tid);
    stage_half(sB + 16384 + 8192, gB + (size_t)128 * K + 64, K, tid);
    stage_half(sA + 16384,        gA + 64,                   K, tid);
    asm volatile("s_waitcnt vmcnt(6)" ::: "memory");
  } else {
    asm volatile("s_waitcnt vmcnt(0)" ::: "memory");
  }
  __builtin_amdgcn_s_barrier();

  for (int t = 0; t < NT; ++t) {
    const int d = t & 1;
    u16* aB = sA + d * 16384 + wm * 8192;
    u16* bB = sB + d * 16384 + (wn >> 1) * 8192 + (wn & 1) * 4096;

    s16x8 aF[4][2], bF[4][2];

    // ---------- phase 1 ----------
    #pragma unroll
    for (int j = 0; j < 2; ++j) {
      bF[j][0] = *(const s16x8*)(bB + j * 1024 + rowoff + xt0);
      bF[j][1] = *(const s16x8*)(bB + j * 1024 + rowoff + xt1);
    }
    #pragma unroll
    for (int i = 0; i < 4; ++i) {
      aF[i][0] = *(const s16x8*)(aB + i * 1024 + rowoff + xt0);
      aF[i][1] = *(const s16x8*)(aB + i * 1024 + rowoff + xt1);
    }
    if (t + 1 < NT)
      stage_half(sA + (d ^ 1) * 16384 + 8192,
                 gA + (size_t)128 * K + (size_t)(t + 1) * 64, K, tid);
    __builtin_amdgcn_s_barrier();
    asm volatile("s_waitcnt lgkmcnt(0)" ::: "memory");
    __builtin_amdgcn_s_setprio(1);
    MFMA_QUAD(0, 0)
    __builtin_amdgcn_s_setprio(0);
    __builtin_amdgcn_s_barrier();

    // ---------- phase 2 ----------
    #pragma unroll
    for (int j = 2; j < 4; ++j) {
      bF[j][0] = *(const s16x8*)(bB + j * 1024 + rowoff + xt0);
      bF[j][1] = *(const s16x8*)(bB + j * 1024 + rowoff + xt1);
    }
    __builtin_amdgcn_s_barrier();
    asm volatile("s_waitcnt lgkmcnt(0)" ::: "memory");
    __builtin_amdgcn_s_setprio(1);
    MFMA_QUAD(0, 2)
    __builtin_amdgcn_s_setprio(0);
    __builtin_amdgcn_s_barrier();

    // ---------- phase 3 ----------
    #pragma unroll
    for (int i = 0; i < 4; ++i) {
      aF[i][0] = *(const s16x8*)(aB + 4096 + i * 1024 + rowoff + xt0);
      aF[i][1] = *(const s16x8*)(aB + 4096 + i * 1024 + rowoff + xt1);
    }
    if (t + 2 < NT) {
      stage_half(sB + d * 16384,        gB + (size_t)(t + 2) * 64,                   K, tid);
      stage_half(sB + d * 16384 + 8192, gB + (size_t)128 * K + (size_t)(t + 2) * 64, K, tid);
    }
    __builtin_amdgcn_s_barrier();
    asm volatile("s_waitcnt lgkmcnt(0)" ::: "memory");
    __builtin_amdgcn_s_setprio(1);
    MFMA_QUAD(4, 0)
    __builtin_amdgcn_s_setprio(0);
    __builtin_amdgcn_s_barrier();

    // ---------- phase 4 ----------
    if (t + 2 < NT)
      stage_half(sA + d * 16384, gA + (size_t)(t + 2) * 64, K, tid);
    __builtin_amdgcn_s_barrier();
    asm volatile("s_waitcnt lgkmcnt(0)" ::: "memory");
    __builtin_amdgcn_s_setprio(1);
    MFMA_QUAD(4, 2)
    __builtin_amdgcn_s_setprio(0);
    if (t + 2 < NT) asm volatile("s_waitcnt vmcnt(6)" ::: "memory");
    else            asm volatile("s_waitcnt vmcnt(0)" ::: "memory");
    __builtin_amdgcn_s_barrier();
  }

  #pragma unroll
  for (int i = 0; i < 8; ++i)
    #pragma unroll
    for (int j = 0; j < 4; ++j)
      #pragma unroll
      for (int r = 0; r < 4; ++r) {
        int m = m0 + wm * 128 + i * 16 + lg * 4 + r;
        int n = n0 + wn * 64 + j * 16 + lc;
        float v = acc[i][j][r];
        if (EPI == 0) {
          v = fminf(fmaxf(v, -CLIPV), CLIPV);
          ((u16*)Cout)[(size_t)m * N + n] = f2bf(v);
        } else {
          ((float*)Cout)[(size_t)m * N + n] = v;
        }
      }
}

// ---------------- kernel 4: LN(q), LN(k) over D=4096 + head relayout of q,k ----------------
__device__ inline void unpack8(uint4 u, float* f) {
  const u16* p = (const u16*)&u;
  #pragma unroll
  for (int j = 0; j < 8; ++j) f[j] = bf2f(p[j]);
}

__global__ void k_ln_reorder(const u16* __restrict__ qkv,
                             const float* __restrict__ qw, const float* __restrict__ qb,
                             const float* __restrict__ kw, const float* __restrict__ kb,
                             u16* __restrict__ Qo, u16* __restrict__ Ko) {
  const int row = blockIdx.x;               // 0..B*S-1
  const int b = row >> 11, s = row & 2047;
  const int t = threadIdx.x;
  const int lane = t & 63, w = t >> 6;
  const uint4* base = (const uint4*)(qkv + (size_t)row * (3 * DD));  // 1536 x uint4

  __shared__ float redsum[8], redss[8];

  uint4 q4[2], k4[2];
  q4[0] = base[t];        q4[1] = base[256 + t];
  k4[0] = base[512 + t];  k4[1] = base[768 + t];

  float qx[16], kx[16];
  unpack8(q4[0], qx); unpack8(q4[1], qx + 8);
  unpack8(k4[0], kx); unpack8(k4[1], kx + 8);

  float qs = 0.f, qss = 0.f, ks = 0.f, kss = 0.f;
  #pragma unroll
  for (int i = 0; i < 16; ++i) {
    qs += qx[i]; qss += qx[i] * qx[i];
    ks += kx[i]; kss += kx[i] * kx[i];
  }
  #pragma unroll
  for (int off = 1; off < 64; off <<= 1) {
    qs  += __shfl_xor(qs, off);  qss += __shfl_xor(qss, off);
    ks  += __shfl_xor(ks, off);  kss += __shfl_xor(kss, off);
  }
  if (lane == 0) { redsum[w] = qs; redss[w] = qss; redsum[4 + w] = ks; redss[4 + w] = kss; }
  __syncthreads();
  float qsum = redsum[0] + redsum[1] + redsum[2] + redsum[3];
  float qs2  = redss[0]  + redss[1]  + redss[2]  + redss[3];
  float ksum = redsum[4] + redsum[5] + redsum[6] + redsum[7];
  float ks2  = redss[4]  + redss[5]  + redss[6]  + redss[7];
  const float inv = 1.0f / (float)DD;
  float qmu = qsum * inv, qvar = qs2 * inv - qmu * qmu;
  float kmu = ksum * inv, kvar = ks2 * inv - kmu * kmu;
  float qrs = rsqrtf(qvar + LN_EPS_);
  float krs = rsqrtf(kvar + LN_EPS_);

  #pragma unroll
  for (int ch = 0; ch < 2; ++ch) {
    int c0 = ch * 2048 + t * 8;
    int hh = c0 >> 7, hd0 = c0 & 127;
    size_t idx = (((size_t)b * HH + hh) * SS + s) * HDD + hd0;
    {
      float4 w0 = *(const float4*)(qw + c0), w1 = *(const float4*)(qw + c0 + 4);
      float4 b0 = *(const float4*)(qb + c0), b1 = *(const float4*)(qb + c0 + 4);
      float wa[8] = {w0.x, w0.y, w0.z, w0.w, w1.x, w1.y, w1.z, w1.w};
      float ba[8] = {b0.x, b0.y, b0.z, b0.w, b1.x, b1.y, b1.z, b1.w};
      u16 tmp[8];
      #pragma unroll
      for (int j = 0; j < 8; ++j)
        tmp[j] = f2bf((qx[ch * 8 + j] - qmu) * qrs * wa[j] + ba[j]);
      *(uint4*)(Qo + idx) = *(const uint4*)tmp;
    }
    {
      float4 w0 = *(const float4*)(kw + c0), w1 = *(const float4*)(kw + c0 + 4);
      float4 b0 = *(const float4*)(kb + c0), b1 = *(const float4*)(kb + c0 + 4);
      float wa[8] = {w0.x, w0.y, w0.z, w0.w, w1.x, w1.y, w1.z, w1.w};
      float ba[8] = {b0.x, b0.y, b0.z, b0.w, b1.x, b1.y, b1.z, b1.w};
      u16 tmp[8];
      #pragma unroll
      for (int j = 0; j < 8; ++j)
        tmp[j] = f2bf((kx[ch * 8 + j] - kmu) * krs * wa[j] + ba[j]);
      *(uint4*)(Ko + idx) = *(const uint4*)tmp;
    }
  }
}

// ---------------- kernel 4b: V slice of qkv -> V^T [B][H][HD][S] ----------------
// tile: 64 s x 64 hd per block, padded LDS, coalesced uint2 both sides.
__global__ void k_transpose_v(const u16* __restrict__ qkv, u16* __restrict__ Vt) {
  __shared__ u16 ls[64 * 65];
  const int s0 = blockIdx.x * 64;
  const int hd0 = blockIdx.y * 64;
  const int bh = blockIdx.z;
  const int b = bh >> 5, h = bh & 31;
  const int t = threadIdx.x;
  const u16* src = qkv + (size_t)(b * SS + s0) * (3 * DD) + 2 * DD + h * HDD + hd0;
  #pragma unroll
  for (int it = 0; it < 4; ++it) {
    int idx = it * 256 + t;
    int sr = idx >> 4, hc = idx & 15;
    uint2 v = *(const uint2*)(src + (size_t)sr * (3 * DD) + hc * 4);
    const u16* pv = (const u16*)&v;
    #pragma unroll
    for (int j = 0; j < 4; ++j) ls[sr * 65 + hc * 4 + j] = pv[j];
  }
  __syncthreads();
  u16* dst = Vt + ((size_t)bh * HDD + hd0) * SS + s0;
  #pragma unroll
  for (int it = 0; it < 4; ++it) {
    int idx = it * 256 + t;
    int hd = idx >> 4, sc = idx & 15;
    u16 tmp[4];
    #pragma unroll
    for (int j = 0; j < 4; ++j) tmp[j] = ls[(4 * sc + j) * 65 + hd];
    *(uint2*)(dst + (size_t)hd * SS + 4 * sc) = *(const uint2*)tmp;
  }
}

// ---------------- kernel 5: flash attention with ALiBi + causal ----------------
// Swapped QK^T: S^T = mfma(A=K, B=Q) -> lane holds S^T[kv][q=lc].
// PV as O^T = mfma(A=V^T, B=P^T): V^T staged row-major from global V^T via
// swizzled-source global_load_lds; P^T via cvt_pk -> ds_write_b64 (swizzled).
// Lane owns q-column lc: softmax rescale + 1/l need no shuffles.
__global__ void k_attn(const u16* __restrict__ Qg, const u16* __restrict__ Kg,
                       const u16* __restrict__ Vt, u16* __restrict__ Og) {
  const int qt = blockIdx.x;                // q tile (64 rows)
  const int bh = blockIdx.y;                // b*H + h
  const int b = bh >> 5, h = bh & 31;
  const int t = threadIdx.x;
  const int lane = t & 63, w = t >> 6;
  const int lg = lane >> 4, lc = lane & 15;
  const float slope = exp2f(-0.25f * (float)(h + 1));

  __shared__ u16 lK[8192];                  // [64 kv][128 d], 16B granule ^ (row&7)
  __shared__ u16 lV[8192];                  // V^T [128 hd][64 kv], 16B granule ^ (row&7)
  __shared__ u16 lP[4][1024];               // per-wave P^T: [16 q][64 kv], 8B granule ^ (2*(q&7))

  const int q0 = qt * 64 + w * 16;
  const size_t bhS = (size_t)bh * SS;
  const u16* Kbase = Kg + bhS * HDD;
  const u16* Vbase = Vt + bhS * HDD;        // [128 hd][2048 s] for this bh

  s16x8 qf[4];
  {
    const u16* qrow = Qg + (bhS + q0 + lc) * HDD;
    #pragma unroll
    for (int kt = 0; kt < 4; ++kt) qf[kt] = *(const s16x8*)(qrow + kt * 32 + lg * 8);
  }

  f32x4 ot[8];                              // O^T[hd = hf*16 + lg*4 + r][q = lc]
  #pragma unroll
  for (int hf = 0; hf < 8; ++hf) ot[hf] = (f32x4){0.f, 0.f, 0.f, 0.f};
  float m_r = -1e30f, l_r = 0.f;

  for (int kv0 = 0; kv0 <= qt * 64; kv0 += 64) {
    // stage K tile: rows kv (128 u16/row = 16 slots), source pre-swizzled
    #pragma unroll
    for (int it = 0; it < 4; ++it) {
      int sl = it * 256 + t;                 // 0..1023
      int row = sl >> 4, k16 = sl & 15;
      gload_lds16(Kbase + (size_t)(kv0 + row) * HDD + ((k16 ^ (row & 7)) * 8),
                  &lK[sl * 8]);
    }
    // stage V^T tile: rows hd (64 u16/row = 8 slots), source pre-swizzled
    #pragma unroll
    for (int it = 0; it < 4; ++it) {
      int sl = it * 256 + t;                 // 0..1023
      int row = sl >> 3, k8 = sl & 7;
      gload_lds16(Vbase + (size_t)row * SS + kv0 + ((k8 ^ (row & 7)) * 8),
                  &lV[sl * 8]);
    }
    __syncthreads();

    // QK^T (swapped): lane holds S^T(kv = i*16 + lg*4 + r, q = lc)
    f32x4 st[4];
    #pragma unroll
    for (int i = 0; i < 4; ++i) {
      st[i] = (f32x4){0.f, 0.f, 0.f, 0.f};
      #pragma unroll
      for (int kt = 0; kt < 4; ++kt) {
        int r = i * 16 + lc;
        const s16x8 ka = *(const s16x8*)&lK[r * 128 + (((kt * 4 + lg) ^ (r & 7)) * 8)];
        st[i] = mfma16(ka, qf[kt], st[i]);
      }
    }

    // scores + ALiBi + causal mask
    float sc[4][4];
    float pm = -1e30f;
    const int qg = q0 + lc;
    #pragma unroll
    for (int i = 0; i < 4; ++i)
      #pragma unroll
      for (int r = 0; r < 4; ++r) {
        int kv = kv0 + i * 16 + lg * 4 + r;
        float x = (kv <= qg) ? st[i][r] * SCALE_ - slope * (float)(qg - kv) : -1e30f;
        sc[i][r] = x;
        pm = fmaxf(pm, x);
      }
    pm = fmaxf(pm, __shfl_xor(pm, 16));
    pm = fmaxf(pm, __shfl_xor(pm, 32));
    float m_new = fmaxf(m_r, pm);
    float alpha = exp2f((m_r - m_new) * LOG2E_);
    float rsum = 0.f;
    #pragma unroll
    for (int i = 0; i < 4; ++i) {
      float p0 = exp2f((sc[i][0] - m_new) * LOG2E_);
      float p1 = exp2f((sc[i][1] - m_new) * LOG2E_);
      float p2 = exp2f((sc[i][2] - m_new) * LOG2E_);
      float p3 = exp2f((sc[i][3] - m_new) * LOG2E_);
      rsum += (p0 + p1) + (p2 + p3);
      u32 dlo, dhi;
      asm("v_cvt_pk_bf16_f32 %0, %1, %2" : "=v"(dlo) : "v"(p0), "v"(p1));
      asm("v_cvt_pk_bf16_f32 %0, %1, %2" : "=v"(dhi) : "v"(p2), "v"(p3));
      // P^T[q=lc][kv = 16i+4lg .. +3], 8B granule index (4i+lg) ^ (2*(lc&7))
      int addr = lc * 64 + (((4 * i + lg) ^ (2 * (lc & 7))) * 4);
      uint2 val; val.x = dlo; val.y = dhi;
      *(uint2*)&lP[w][addr] = val;
    }
    rsum += __shfl_xor(rsum, 16);
    rsum += __shfl_xor(rsum, 32);
    l_r = l_r * alpha + rsum;
    m_r = m_new;

    // rescale O^T: lane's column q=lc -> own alpha, no shuffle
    #pragma unroll
    for (int hf = 0; hf < 8; ++hf) {
      ot[hf][0] *= alpha; ot[hf][1] *= alpha; ot[hf][2] *= alpha; ot[hf][3] *= alpha;
    }

    // PV: O^T[hd][q] += V^T[hd][kv] * P^T[kv][q]
    #pragma unroll
    for (int ks = 0; ks < 2; ++ks) {
      const int m = 4 * ks + lg;            // 16B granule along kv
      const s16x8 pa = *(const s16x8*)&lP[w][lc * 64 + ((m ^ (lc & 7)) * 8)];
      #pragma unroll
      for (int hf = 0; hf < 8; ++hf) {
        int row = hf * 16 + lc;
        const s16x8 vb = *(const s16x8*)&lV[row * 64 + ((m ^ (row & 7)) * 8)];
        ot[hf] = mfma16(vb, pa, ot[hf]);
      }
    }
    __syncthreads();
  }

  // epilogue: normalize by l (lane-local), store 8B chunks (4 contiguous hd)
  float linv = 1.f / l_r;
  const size_t obase = ((size_t)(b * SS + q0 + lc)) * DD + h * HDD;
  #pragma unroll
  for (int hf = 0; hf < 8; ++hf) {
    u16 tmp[4];
    #pragma unroll
    for (int r = 0; r < 4; ++r) tmp[r] = f2bf(ot[hf][r] * linv);
    *(uint2*)&Og[obase + hf * 16 + lg * 4] = *(const uint2*)tmp;
  }
}

// ---------------- launch ----------------
extern "C" void kernel_launch(void* const* d_in, const int* in_sizes, int n_in,
                              void* d_out, int out_size, void* d_ws, size_t ws_size,
                              hipStream_t stream) {
  const float* hidden = (const float*)d_in[0];
  const float* Wqkv   = (const float*)d_in[1];
  const float* Wout   = (const float*)d_in[2];
  const float* qw     = (const float*)d_in[3];
  const float* qb     = (const float*)d_in[4];
  const float* kw     = (const float*)d_in[5];
  const float* kb     = (const float*)d_in[6];
  float* out = (float*)d_out;
  char* ws = (char*)d_ws;

  // workspace layout (total 256 MB)
  u16* Xb    = (u16*)(ws);                    // 32 MB (reused as attn_out)
  u16* WqkvT = (u16*)(ws + 33554432);         // 96 MB (reused as Q,K,Vt after GEMM)
  u16* Qb    = (u16*)(ws + 33554432);
  u16* Kb    = (u16*)(ws + 67108864);
  u16* Vtb   = (u16*)(ws + 100663296);        // V^T [B][H][HD][S]
  u16* WoutT = (u16*)(ws + 134217728);        // 32 MB
  u16* qkv   = (u16*)(ws + 167772160);        // 96 MB
  u16* attnO = Xb;

  k_cvt_bf16<<<8192, 256, 0, stream>>>(hidden, Xb, 2097152);
  k_transpose_cvt<<<dim3(12288 / 32, 4096 / 32), 256, 0, stream>>>(Wqkv, WqkvT, 4096, 12288);
  k_transpose_cvt<<<dim3(4096 / 32, 4096 / 32), 256, 0, stream>>>(Wout, WoutT, 4096, 4096);
  // QKV GEMM: M=4096, N=12288, K=4096 -> 16 x 48 = 768 blocks
  k_gemm256<0><<<768, 512, 0, stream>>>(Xb, WqkvT, qkv, 4096, 12288, 4096, 48);
  k_ln_reorder<<<4096, 256, 0, stream>>>(qkv, qw, qb, kw, kb, Qb, Kb);
  k_transpose_v<<<dim3(SS / 64, HDD / 64, BB * HH), 256, 0, stream>>>(qkv, Vtb);
  k_attn<<<dim3(32, 64), 256, 0, stream>>>(Qb, Kb, Vtb, attnO);
  // out-proj GEMM: M=4096, N=4096, K=4096 -> 16 x 16 = 256 blocks
  k_gemm256<1><<<256, 512, 0, stream>>>(attnO, WoutT, out, 4096, 4096, 4096, 16);
}

// Round 4
// 893.695 us; speedup vs baseline: 2.2071x; 1.0459x over previous
//
#include <hip/hip_runtime.h>
#include <hip/hip_bf16.h>
#include <stdint.h>

// Problem constants
#define BB 2
#define SS 2048
#define DD 4096
#define HH 32
#define HDD 128

typedef unsigned short u16;
typedef unsigned int u32;

constexpr float CLIPV  = 8.0f;
constexpr float LN_EPS_ = 1e-5f;
constexpr float SCALE_ = 0.08838834764831845f;   // 1/sqrt(128)
constexpr float LOG2E_ = 1.4426950408889634f;

using f32x4 = __attribute__((ext_vector_type(4))) float;
using s16x8 = __attribute__((ext_vector_type(8))) short;

__device__ inline u16 f2bf(float f) {
  union { float f; u32 u; } v; v.f = f;
  u32 r = (v.u + 0x7FFFu + ((v.u >> 16) & 1u)) >> 16;
  return (u16)r;
}
__device__ inline float bf2f(u16 u) {
  union { u32 u; float f; } v; v.u = ((u32)u) << 16;
  return v.f;
}

typedef __attribute__((address_space(1))) void gvoid;
typedef __attribute__((address_space(3))) void lvoid;
__device__ inline void gload_lds16(const void* g, void* l) {
  __builtin_amdgcn_global_load_lds((gvoid*)g, (lvoid*)l, 16, 0, 0);
}

__device__ inline f32x4 mfma16(s16x8 a, s16x8 b, f32x4 c) {
  return __builtin_amdgcn_mfma_f32_16x16x32_bf16(a, b, c, 0, 0, 0);
}

// ---------------- kernel 1: f32 -> bf16 elementwise ----------------
__global__ void k_cvt_bf16(const float* __restrict__ in, u16* __restrict__ out, int nvec) {
  int i = blockIdx.x * 256 + threadIdx.x;
  if (i >= nvec) return;
  float4 a = ((const float4*)in)[i * 2];
  float4 b = ((const float4*)in)[i * 2 + 1];
  u16 tmp[8];
  tmp[0] = f2bf(a.x); tmp[1] = f2bf(a.y); tmp[2] = f2bf(a.z); tmp[3] = f2bf(a.w);
  tmp[4] = f2bf(b.x); tmp[5] = f2bf(b.y); tmp[6] = f2bf(b.z); tmp[7] = f2bf(b.w);
  ((uint4*)out)[i] = *(const uint4*)tmp;
}

// ---------------- kernel 2: transpose + convert: src f32 [R][C] -> dst bf16 [C][R] ----------------
__global__ void k_transpose_cvt(const float* __restrict__ src, u16* __restrict__ dst, int R, int C) {
  __shared__ float tile[32][33];
  int c0 = blockIdx.x * 32, r0 = blockIdx.y * 32;
  int tx = threadIdx.x & 31, ty = threadIdx.x >> 5;   // 32 x 8
  #pragma unroll
  for (int i = 0; i < 32; i += 8)
    tile[ty + i][tx] = src[(size_t)(r0 + ty + i) * C + (c0 + tx)];
  __syncthreads();
  #pragma unroll
  for (int i = 0; i < 32; i += 8)
    dst[(size_t)(c0 + ty + i) * R + (r0 + tx)] = f2bf(tile[tx][ty + i]);
}

// ---------------- 256x256 8-phase GEMM: C = A[M][K] * Bt[N][K]^T ----------------
// XCD mapping: each XCD owns a contiguous bx-COLUMN band, by fastest.
// -> the <=2 active B-panels per XCD stay L2-resident (16x reuse, HBM once);
//    A (32 MB) is L3-resident for cross-XCD reuse.
__device__ __forceinline__ void stage_half(u16* ldsHalf, const u16* g, int K, int tid) {
  #pragma unroll
  for (int it = 0; it < 2; ++it) {
    int p = (it << 9) + tid;           // 16B slot index 0..1023
    int row = p >> 3;                  // 0..127
    int slotk = (p & 7) ^ (row & 7);   // inverse-swizzled source slot
    gload_lds16(g + (size_t)row * K + (slotk << 3), ldsHalf + ((size_t)p << 3));
  }
}

#define MFMA_QUAD(MB, JB)                                                     \
  _Pragma("unroll")                                                           \
  for (int i_ = 0; i_ < 4; ++i_) {                                            \
    _Pragma("unroll")                                                         \
    for (int jj_ = 0; jj_ < 2; ++jj_) {                                       \
      acc[(MB) + i_][(JB) + jj_] =                                            \
          mfma16(aF[i_][0], bF[(JB) + jj_][0], acc[(MB) + i_][(JB) + jj_]);   \
      acc[(MB) + i_][(JB) + jj_] =                                            \
          mfma16(aF[i_][1], bF[(JB) + jj_][1], acc[(MB) + i_][(JB) + jj_]);   \
    }                                                                         \
  }

template <int EPI>   // 0: clip to +-8, store bf16 ; 1: store f32
__launch_bounds__(512)
__global__ void k_gemm256(const u16* __restrict__ A, const u16* __restrict__ Bt,
                          void* __restrict__ Cout, int M, int N, int K, int nBY) {
  __shared__ u16 sA[32768];   // 2 bufs x 2 halves x 128x64
  __shared__ u16 sB[32768];
  const int tid = threadIdx.x;
  const int lane = tid & 63, w = tid >> 6;
  const int wm = w >> 2, wn = w & 3;          // 2 x 4 waves
  const int lg = lane >> 4, lc = lane & 15;

  // column-major-within-XCD bijective swizzle (nwg % 8 == 0)
  const int nwg = gridDim.x;
  const int cpx = nwg >> 3;
  const int id2 = (blockIdx.x & 7) * cpx + (blockIdx.x >> 3);
  const int bx = id2 / nBY, by = id2 % nBY;
  const int m0 = by * 256, n0 = bx * 256;

  const int NT = K >> 6;
  const u16* gA = A  + (size_t)m0 * K;
  const u16* gB = Bt + (size_t)n0 * K;

  const int xt0 = ((lg) ^ (lc & 7)) * 8;
  const int xt1 = xt0 ^ 32;
  const int rowoff = lc * 64;

  f32x4 acc[8][4];
  #pragma unroll
  for (int i = 0; i < 8; ++i)
    #pragma unroll
    for (int j = 0; j < 4; ++j) acc[i][j] = (f32x4){0.f, 0.f, 0.f, 0.f};

  stage_half(sA,        gA,                    K, tid);
  stage_half(sA + 8192, gA + (size_t)128 * K,  K, tid);
  stage_half(sB,        gB,                    K, tid);
  stage_half(sB + 8192, gB + (size_t)128 * K,  K, tid);
  if (NT > 1) {
    stage_half(sB + 16384,        gB + 64,                   K, tid);
    stage_half(sB + 16384 + 8192, gB + (size_t)128 * K + 64, K, tid);
    stage_half(sA + 16384,        gA + 64,                   K, tid);
    asm volatile("s_waitcnt vmcnt(6)" ::: "memory");
  } else {
    asm volatile("s_waitcnt vmcnt(0)" ::: "memory");
  }
  __builtin_amdgcn_s_barrier();

  for (int t = 0; t < NT; ++t) {
    const int d = t & 1;
    u16* aB = sA + d * 16384 + wm * 8192;
    u16* bB = sB + d * 16384 + (wn >> 1) * 8192 + (wn & 1) * 4096;

    s16x8 aF[4][2], bF[4][2];

    // ---------- phase 1 ----------
    #pragma unroll
    for (int j = 0; j < 2; ++j) {
      bF[j][0] = *(const s16x8*)(bB + j * 1024 + rowoff + xt0);
      bF[j][1] = *(const s16x8*)(bB + j * 1024 + rowoff + xt1);
    }
    #pragma unroll
    for (int i = 0; i < 4; ++i) {
      aF[i][0] = *(const s16x8*)(aB + i * 1024 + rowoff + xt0);
      aF[i][1] = *(const s16x8*)(aB + i * 1024 + rowoff + xt1);
    }
    if (t + 1 < NT)
      stage_half(sA + (d ^ 1) * 16384 + 8192,
                 gA + (size_t)128 * K + (size_t)(t + 1) * 64, K, tid);
    __builtin_amdgcn_s_barrier();
    asm volatile("s_waitcnt lgkmcnt(0)" ::: "memory");
    __builtin_amdgcn_s_setprio(1);
    MFMA_QUAD(0, 0)
    __builtin_amdgcn_s_setprio(0);
    __builtin_amdgcn_s_barrier();

    // ---------- phase 2 ----------
    #pragma unroll
    for (int j = 2; j < 4; ++j) {
      bF[j][0] = *(const s16x8*)(bB + j * 1024 + rowoff + xt0);
      bF[j][1] = *(const s16x8*)(bB + j * 1024 + rowoff + xt1);
    }
    __builtin_amdgcn_s_barrier();
    asm volatile("s_waitcnt lgkmcnt(0)" ::: "memory");
    __builtin_amdgcn_s_setprio(1);
    MFMA_QUAD(0, 2)
    __builtin_amdgcn_s_setprio(0);
    __builtin_amdgcn_s_barrier();

    // ---------- phase 3 ----------
    #pragma unroll
    for (int i = 0; i < 4; ++i) {
      aF[i][0] = *(const s16x8*)(aB + 4096 + i * 1024 + rowoff + xt0);
      aF[i][1] = *(const s16x8*)(aB + 4096 + i * 1024 + rowoff + xt1);
    }
    if (t + 2 < NT) {
      stage_half(sB + d * 16384,        gB + (size_t)(t + 2) * 64,                   K, tid);
      stage_half(sB + d * 16384 + 8192, gB + (size_t)128 * K + (size_t)(t + 2) * 64, K, tid);
    }
    __builtin_amdgcn_s_barrier();
    asm volatile("s_waitcnt lgkmcnt(0)" ::: "memory");
    __builtin_amdgcn_s_setprio(1);
    MFMA_QUAD(4, 0)
    __builtin_amdgcn_s_setprio(0);
    __builtin_amdgcn_s_barrier();

    // ---------- phase 4 ----------
    if (t + 2 < NT)
      stage_half(sA + d * 16384, gA + (size_t)(t + 2) * 64, K, tid);
    __builtin_amdgcn_s_barrier();
    asm volatile("s_waitcnt lgkmcnt(0)" ::: "memory");
    __builtin_amdgcn_s_setprio(1);
    MFMA_QUAD(4, 2)
    __builtin_amdgcn_s_setprio(0);
    if (t + 2 < NT) asm volatile("s_waitcnt vmcnt(6)" ::: "memory");
    else            asm volatile("s_waitcnt vmcnt(0)" ::: "memory");
    __builtin_amdgcn_s_barrier();
  }

  #pragma unroll
  for (int i = 0; i < 8; ++i)
    #pragma unroll
    for (int j = 0; j < 4; ++j)
      #pragma unroll
      for (int r = 0; r < 4; ++r) {
        int m = m0 + wm * 128 + i * 16 + lg * 4 + r;
        int n = n0 + wn * 64 + j * 16 + lc;
        float v = acc[i][j][r];
        if (EPI == 0) {
          v = fminf(fmaxf(v, -CLIPV), CLIPV);
          ((u16*)Cout)[(size_t)m * N + n] = f2bf(v);
        } else {
          ((float*)Cout)[(size_t)m * N + n] = v;
        }
      }
}

// ---------------- kernel 4: LN(q), LN(k) over D=4096 + head relayout of q,k ----------------
__device__ inline void unpack8(uint4 u, float* f) {
  const u16* p = (const u16*)&u;
  #pragma unroll
  for (int j = 0; j < 8; ++j) f[j] = bf2f(p[j]);
}

__global__ void k_ln_reorder(const u16* __restrict__ qkv,
                             const float* __restrict__ qw, const float* __restrict__ qb,
                             const float* __restrict__ kw, const float* __restrict__ kb,
                             u16* __restrict__ Qo, u16* __restrict__ Ko) {
  const int row = blockIdx.x;               // 0..B*S-1
  const int b = row >> 11, s = row & 2047;
  const int t = threadIdx.x;
  const int lane = t & 63, w = t >> 6;
  const uint4* base = (const uint4*)(qkv + (size_t)row * (3 * DD));  // 1536 x uint4

  __shared__ float redsum[8], redss[8];

  uint4 q4[2], k4[2];
  q4[0] = base[t];        q4[1] = base[256 + t];
  k4[0] = base[512 + t];  k4[1] = base[768 + t];

  float qx[16], kx[16];
  unpack8(q4[0], qx); unpack8(q4[1], qx + 8);
  unpack8(k4[0], kx); unpack8(k4[1], kx + 8);

  float qs = 0.f, qss = 0.f, ks = 0.f, kss = 0.f;
  #pragma unroll
  for (int i = 0; i < 16; ++i) {
    qs += qx[i]; qss += qx[i] * qx[i];
    ks += kx[i]; kss += kx[i] * kx[i];
  }
  #pragma unroll
  for (int off = 1; off < 64; off <<= 1) {
    qs  += __shfl_xor(qs, off);  qss += __shfl_xor(qss, off);
    ks  += __shfl_xor(ks, off);  kss += __shfl_xor(kss, off);
  }
  if (lane == 0) { redsum[w] = qs; redss[w] = qss; redsum[4 + w] = ks; redss[4 + w] = kss; }
  __syncthreads();
  float qsum = redsum[0] + redsum[1] + redsum[2] + redsum[3];
  float qs2  = redss[0]  + redss[1]  + redss[2]  + redss[3];
  float ksum = redsum[4] + redsum[5] + redsum[6] + redsum[7];
  float ks2  = redss[4]  + redss[5]  + redss[6]  + redss[7];
  const float inv = 1.0f / (float)DD;
  float qmu = qsum * inv, qvar = qs2 * inv - qmu * qmu;
  float kmu = ksum * inv, kvar = ks2 * inv - kmu * kmu;
  float qrs = rsqrtf(qvar + LN_EPS_);
  float krs = rsqrtf(kvar + LN_EPS_);

  #pragma unroll
  for (int ch = 0; ch < 2; ++ch) {
    int c0 = ch * 2048 + t * 8;
    int hh = c0 >> 7, hd0 = c0 & 127;
    size_t idx = (((size_t)b * HH + hh) * SS + s) * HDD + hd0;
    {
      float4 w0 = *(const float4*)(qw + c0), w1 = *(const float4*)(qw + c0 + 4);
      float4 b0 = *(const float4*)(qb + c0), b1 = *(const float4*)(qb + c0 + 4);
      float wa[8] = {w0.x, w0.y, w0.z, w0.w, w1.x, w1.y, w1.z, w1.w};
      float ba[8] = {b0.x, b0.y, b0.z, b0.w, b1.x, b1.y, b1.z, b1.w};
      u16 tmp[8];
      #pragma unroll
      for (int j = 0; j < 8; ++j)
        tmp[j] = f2bf((qx[ch * 8 + j] - qmu) * qrs * wa[j] + ba[j]);
      *(uint4*)(Qo + idx) = *(const uint4*)tmp;
    }
    {
      float4 w0 = *(const float4*)(kw + c0), w1 = *(const float4*)(kw + c0 + 4);
      float4 b0 = *(const float4*)(kb + c0), b1 = *(const float4*)(kb + c0 + 4);
      float wa[8] = {w0.x, w0.y, w0.z, w0.w, w1.x, w1.y, w1.z, w1.w};
      float ba[8] = {b0.x, b0.y, b0.z, b0.w, b1.x, b1.y, b1.z, b1.w};
      u16 tmp[8];
      #pragma unroll
      for (int j = 0; j < 8; ++j)
        tmp[j] = f2bf((kx[ch * 8 + j] - kmu) * krs * wa[j] + ba[j]);
      *(uint4*)(Ko + idx) = *(const uint4*)tmp;
    }
  }
}

// ---------------- kernel 4b: V slice of qkv -> V^T [B][H][HD][S] ----------------
__global__ void k_transpose_v(const u16* __restrict__ qkv, u16* __restrict__ Vt) {
  __shared__ u16 ls[64 * 65];
  const int s0 = blockIdx.x * 64;
  const int hd0 = blockIdx.y * 64;
  const int bh = blockIdx.z;
  const int b = bh >> 5, h = bh & 31;
  const int t = threadIdx.x;
  const u16* src = qkv + (size_t)(b * SS + s0) * (3 * DD) + 2 * DD + h * HDD + hd0;
  #pragma unroll
  for (int it = 0; it < 4; ++it) {
    int idx = it * 256 + t;
    int sr = idx >> 4, hc = idx & 15;
    uint2 v = *(const uint2*)(src + (size_t)sr * (3 * DD) + hc * 4);
    const u16* pv = (const u16*)&v;
    #pragma unroll
    for (int j = 0; j < 4; ++j) ls[sr * 65 + hc * 4 + j] = pv[j];
  }
  __syncthreads();
  u16* dst = Vt + ((size_t)bh * HDD + hd0) * SS + s0;
  #pragma unroll
  for (int it = 0; it < 4; ++it) {
    int idx = it * 256 + t;
    int hd = idx >> 4, sc = idx & 15;
    u16 tmp[4];
    #pragma unroll
    for (int j = 0; j < 4; ++j) tmp[j] = ls[(4 * sc + j) * 65 + hd];
    *(uint2*)(dst + (size_t)hd * SS + 4 * sc) = *(const uint2*)tmp;
  }
}

// ---------------- kernel 5: flash attention with ALiBi + causal ----------------
__global__ void k_attn(const u16* __restrict__ Qg, const u16* __restrict__ Kg,
                       const u16* __restrict__ Vt, u16* __restrict__ Og) {
  const int qt = blockIdx.x;                // q tile (64 rows)
  const int bh = blockIdx.y;                // b*H + h
  const int b = bh >> 5, h = bh & 31;
  const int t = threadIdx.x;
  const int lane = t & 63, w = t >> 6;
  const int lg = lane >> 4, lc = lane & 15;
  const float slope = exp2f(-0.25f * (float)(h + 1));

  __shared__ u16 lK[8192];                  // [64 kv][128 d], 16B granule ^ (row&7)
  __shared__ u16 lV[8192];                  // V^T [128 hd][64 kv], 16B granule ^ (row&7)
  __shared__ u16 lP[4][1024];               // per-wave P^T: [16 q][64 kv], 8B granule ^ (2*(q&7))

  const int q0 = qt * 64 + w * 16;
  const size_t bhS = (size_t)bh * SS;
  const u16* Kbase = Kg + bhS * HDD;
  const u16* Vbase = Vt + bhS * HDD;        // [128 hd][2048 s] for this bh

  s16x8 qf[4];
  {
    const u16* qrow = Qg + (bhS + q0 + lc) * HDD;
    #pragma unroll
    for (int kt = 0; kt < 4; ++kt) qf[kt] = *(const s16x8*)(qrow + kt * 32 + lg * 8);
  }

  f32x4 ot[8];                              // O^T[hd = hf*16 + lg*4 + r][q = lc]
  #pragma unroll
  for (int hf = 0; hf < 8; ++hf) ot[hf] = (f32x4){0.f, 0.f, 0.f, 0.f};
  float m_r = -1e30f, l_r = 0.f;

  for (int kv0 = 0; kv0 <= qt * 64; kv0 += 64) {
    #pragma unroll
    for (int it = 0; it < 4; ++it) {
      int sl = it * 256 + t;                 // 0..1023
      int row = sl >> 4, k16 = sl & 15;
      gload_lds16(Kbase + (size_t)(kv0 + row) * HDD + ((k16 ^ (row & 7)) * 8),
                  &lK[sl * 8]);
    }
    #pragma unroll
    for (int it = 0; it < 4; ++it) {
      int sl = it * 256 + t;                 // 0..1023
      int row = sl >> 3, k8 = sl & 7;
      gload_lds16(Vbase + (size_t)row * SS + kv0 + ((k8 ^ (row & 7)) * 8),
                  &lV[sl * 8]);
    }
    __syncthreads();

    // QK^T (swapped): lane holds S^T(kv = i*16 + lg*4 + r, q = lc)
    f32x4 st[4];
    #pragma unroll
    for (int i = 0; i < 4; ++i) {
      st[i] = (f32x4){0.f, 0.f, 0.f, 0.f};
      #pragma unroll
      for (int kt = 0; kt < 4; ++kt) {
        int r = i * 16 + lc;
        const s16x8 ka = *(const s16x8*)&lK[r * 128 + (((kt * 4 + lg) ^ (r & 7)) * 8)];
        st[i] = mfma16(ka, qf[kt], st[i]);
      }
    }

    // scores + ALiBi + causal mask
    float sc[4][4];
    float pm = -1e30f;
    const int qg = q0 + lc;
    #pragma unroll
    for (int i = 0; i < 4; ++i)
      #pragma unroll
      for (int r = 0; r < 4; ++r) {
        int kv = kv0 + i * 16 + lg * 4 + r;
        float x = (kv <= qg) ? st[i][r] * SCALE_ - slope * (float)(qg - kv) : -1e30f;
        sc[i][r] = x;
        pm = fmaxf(pm, x);
      }
    pm = fmaxf(pm, __shfl_xor(pm, 16));
    pm = fmaxf(pm, __shfl_xor(pm, 32));
    float m_new = fmaxf(m_r, pm);
    float alpha = exp2f((m_r - m_new) * LOG2E_);
    float rsum = 0.f;
    #pragma unroll
    for (int i = 0; i < 4; ++i) {
      float p0 = exp2f((sc[i][0] - m_new) * LOG2E_);
      float p1 = exp2f((sc[i][1] - m_new) * LOG2E_);
      float p2 = exp2f((sc[i][2] - m_new) * LOG2E_);
      float p3 = exp2f((sc[i][3] - m_new) * LOG2E_);
      rsum += (p0 + p1) + (p2 + p3);
      u32 dlo, dhi;
      asm("v_cvt_pk_bf16_f32 %0, %1, %2" : "=v"(dlo) : "v"(p0), "v"(p1));
      asm("v_cvt_pk_bf16_f32 %0, %1, %2" : "=v"(dhi) : "v"(p2), "v"(p3));
      int addr = lc * 64 + (((4 * i + lg) ^ (2 * (lc & 7))) * 4);
      uint2 val; val.x = dlo; val.y = dhi;
      *(uint2*)&lP[w][addr] = val;
    }
    rsum += __shfl_xor(rsum, 16);
    rsum += __shfl_xor(rsum, 32);
    l_r = l_r * alpha + rsum;
    m_r = m_new;

    #pragma unroll
    for (int hf = 0; hf < 8; ++hf) {
      ot[hf][0] *= alpha; ot[hf][1] *= alpha; ot[hf][2] *= alpha; ot[hf][3] *= alpha;
    }

    // PV: O^T[hd][q] += V^T[hd][kv] * P^T[kv][q]
    #pragma unroll
    for (int ks = 0; ks < 2; ++ks) {
      const int m = 4 * ks + lg;            // 16B granule along kv
      const s16x8 pa = *(const s16x8*)&lP[w][lc * 64 + ((m ^ (lc & 7)) * 8)];
      #pragma unroll
      for (int hf = 0; hf < 8; ++hf) {
        int row = hf * 16 + lc;
        const s16x8 vb = *(const s16x8*)&lV[row * 64 + ((m ^ (row & 7)) * 8)];
        ot[hf] = mfma16(vb, pa, ot[hf]);
      }
    }
    __syncthreads();
  }

  // epilogue: normalize by l (lane-local), store 8B chunks (4 contiguous hd)
  float linv = 1.f / l_r;
  const size_t obase = ((size_t)(b * SS + q0 + lc)) * DD + h * HDD;
  #pragma unroll
  for (int hf = 0; hf < 8; ++hf) {
    u16 tmp[4];
    #pragma unroll
    for (int r = 0; r < 4; ++r) tmp[r] = f2bf(ot[hf][r] * linv);
    *(uint2*)&Og[obase + hf * 16 + lg * 4] = *(const uint2*)tmp;
  }
}

// ---------------- launch ----------------
extern "C" void kernel_launch(void* const* d_in, const int* in_sizes, int n_in,
                              void* d_out, int out_size, void* d_ws, size_t ws_size,
                              hipStream_t stream) {
  const float* hidden = (const float*)d_in[0];
  const float* Wqkv   = (const float*)d_in[1];
  const float* Wout   = (const float*)d_in[2];
  const float* qw     = (const float*)d_in[3];
  const float* qb     = (const float*)d_in[4];
  const float* kw     = (const float*)d_in[5];
  const float* kb     = (const float*)d_in[6];
  float* out = (float*)d_out;
  char* ws = (char*)d_ws;

  // workspace layout (total 256 MB)
  u16* Xb    = (u16*)(ws);                    // 32 MB (reused as attn_out)
  u16* WqkvT = (u16*)(ws + 33554432);         // 96 MB (reused as Q,K,Vt after GEMM)
  u16* Qb    = (u16*)(ws + 33554432);
  u16* Kb    = (u16*)(ws + 67108864);
  u16* Vtb   = (u16*)(ws + 100663296);        // V^T [B][H][HD][S]
  u16* WoutT = (u16*)(ws + 134217728);        // 32 MB
  u16* qkv   = (u16*)(ws + 167772160);        // 96 MB
  u16* attnO = Xb;

  k_cvt_bf16<<<8192, 256, 0, stream>>>(hidden, Xb, 2097152);
  k_transpose_cvt<<<dim3(12288 / 32, 4096 / 32), 256, 0, stream>>>(Wqkv, WqkvT, 4096, 12288);
  k_transpose_cvt<<<dim3(4096 / 32, 4096 / 32), 256, 0, stream>>>(Wout, WoutT, 4096, 4096);
  // QKV GEMM: M=4096, N=12288, K=4096 -> grid 768, nBY=16
  k_gemm256<0><<<768, 512, 0, stream>>>(Xb, WqkvT, qkv, 4096, 12288, 4096, 16);
  k_ln_reorder<<<4096, 256, 0, stream>>>(qkv, qw, qb, kw, kb, Qb, Kb);
  k_transpose_v<<<dim3(SS / 64, HDD / 64, BB * HH), 256, 0, stream>>>(qkv, Vtb);
  k_attn<<<dim3(32, 64), 256, 0, stream>>>(Qb, Kb, Vtb, attnO);
  // out-proj GEMM: M=4096, N=4096, K=4096 -> grid 256, nBY=16
  k_gemm256<1><<<256, 512, 0, stream>>>(attnO, WoutT, out, 4096, 4096, 4096, 16);
}

// Round 5
// 882.837 us; speedup vs baseline: 2.2343x; 1.0123x over previous
//
#include <hip/hip_runtime.h>
#include <hip/hip_bf16.h>
#include <stdint.h>

// Problem constants
#define BB 2
#define SS 2048
#define DD 4096
#define HH 32
#define HDD 128

typedef unsigned short u16;
typedef unsigned int u32;

constexpr float CLIPV  = 8.0f;
constexpr float LN_EPS_ = 1e-5f;
constexpr float SCALE_ = 0.08838834764831845f;   // 1/sqrt(128)
constexpr float LOG2E_ = 1.4426950408889634f;

using f32x4 = __attribute__((ext_vector_type(4))) float;
using s16x8 = __attribute__((ext_vector_type(8))) short;

__device__ inline u16 f2bf(float f) {
  union { float f; u32 u; } v; v.f = f;
  u32 r = (v.u + 0x7FFFu + ((v.u >> 16) & 1u)) >> 16;
  return (u16)r;
}
__device__ inline float bf2f(u16 u) {
  union { u32 u; float f; } v; v.u = ((u32)u) << 16;
  return v.f;
}

typedef __attribute__((address_space(1))) void gvoid;
typedef __attribute__((address_space(3))) void lvoid;
__device__ inline void gload_lds16(const void* g, void* l) {
  __builtin_amdgcn_global_load_lds((gvoid*)g, (lvoid*)l, 16, 0, 0);
}

__device__ inline f32x4 mfma16(s16x8 a, s16x8 b, f32x4 c) {
  return __builtin_amdgcn_mfma_f32_16x16x32_bf16(a, b, c, 0, 0, 0);
}

// ---------------- kernel 1: f32 -> bf16 elementwise ----------------
__global__ void k_cvt_bf16(const float* __restrict__ in, u16* __restrict__ out, int nvec) {
  int i = blockIdx.x * 256 + threadIdx.x;
  if (i >= nvec) return;
  float4 a = ((const float4*)in)[i * 2];
  float4 b = ((const float4*)in)[i * 2 + 1];
  u16 tmp[8];
  tmp[0] = f2bf(a.x); tmp[1] = f2bf(a.y); tmp[2] = f2bf(a.z); tmp[3] = f2bf(a.w);
  tmp[4] = f2bf(b.x); tmp[5] = f2bf(b.y); tmp[6] = f2bf(b.z); tmp[7] = f2bf(b.w);
  ((uint4*)out)[i] = *(const uint4*)tmp;
}

// ---------------- kernel 2: transpose + convert: src f32 [R][C] -> dst bf16 [C][R] ----------------
__global__ void k_transpose_cvt(const float* __restrict__ src, u16* __restrict__ dst, int R, int C) {
  __shared__ float tile[32][33];
  int c0 = blockIdx.x * 32, r0 = blockIdx.y * 32;
  int tx = threadIdx.x & 31, ty = threadIdx.x >> 5;   // 32 x 8
  #pragma unroll
  for (int i = 0; i < 32; i += 8)
    tile[ty + i][tx] = src[(size_t)(r0 + ty + i) * C + (c0 + tx)];
  __syncthreads();
  #pragma unroll
  for (int i = 0; i < 32; i += 8)
    dst[(size_t)(c0 + ty + i) * R + (r0 + tx)] = f2bf(tile[tx][ty + i]);
}

// ---------------- 256x256 8-phase GEMM: C = A[M][K] * Bt[N][K]^T ----------------
// Staging schedule (rebalanced): per tile t, p3 stages B01(t+2), p4 stages
// A0+A1(t+2). All 8 loads of tile t+1 were issued during tile t-1 ->
// at end-of-tile vmcnt(8), each load has had >=4 phases to complete.
__device__ __forceinline__ void stage_half(u16* ldsHalf, const u16* g, int K, int tid) {
  #pragma unroll
  for (int it = 0; it < 2; ++it) {
    int p = (it << 9) + tid;           // 16B slot index 0..1023
    int row = p >> 3;                  // 0..127
    int slotk = (p & 7) ^ (row & 7);   // inverse-swizzled source slot
    gload_lds16(g + (size_t)row * K + (slotk << 3), ldsHalf + ((size_t)p << 3));
  }
}

#define MFMA_QUAD(MB, JB)                                                     \
  _Pragma("unroll")                                                           \
  for (int i_ = 0; i_ < 4; ++i_) {                                            \
    _Pragma("unroll")                                                         \
    for (int jj_ = 0; jj_ < 2; ++jj_) {                                       \
      acc[(MB) + i_][(JB) + jj_] =                                            \
          mfma16(aF[i_][0], bF[(JB) + jj_][0], acc[(MB) + i_][(JB) + jj_]);   \
      acc[(MB) + i_][(JB) + jj_] =                                            \
          mfma16(aF[i_][1], bF[(JB) + jj_][1], acc[(MB) + i_][(JB) + jj_]);   \
    }                                                                         \
  }

template <int EPI>   // 0: clip to +-8, store bf16 ; 1: store f32
__launch_bounds__(512)
__global__ void k_gemm256(const u16* __restrict__ A, const u16* __restrict__ Bt,
                          void* __restrict__ Cout, int M, int N, int K, int nBY) {
  __shared__ u16 sA[32768];   // 2 bufs x 2 halves x 128x64
  __shared__ u16 sB[32768];
  const int tid = threadIdx.x;
  const int lane = tid & 63, w = tid >> 6;
  const int wm = w >> 2, wn = w & 3;          // 2 x 4 waves
  const int lg = lane >> 4, lc = lane & 15;

  // column-major-within-XCD bijective swizzle (nwg % 8 == 0)
  const int nwg = gridDim.x;
  const int cpx = nwg >> 3;
  const int id2 = (blockIdx.x & 7) * cpx + (blockIdx.x >> 3);
  const int bx = id2 / nBY, by = id2 % nBY;
  const int m0 = by * 256, n0 = bx * 256;

  const int NT = K >> 6;
  const u16* gA = A  + (size_t)m0 * K;
  const u16* gB = Bt + (size_t)n0 * K;

  const int xt0 = ((lg) ^ (lc & 7)) * 8;
  const int xt1 = xt0 ^ 32;
  const int rowoff = lc * 64;

  f32x4 acc[8][4];
  #pragma unroll
  for (int i = 0; i < 8; ++i)
    #pragma unroll
    for (int j = 0; j < 4; ++j) acc[i][j] = (f32x4){0.f, 0.f, 0.f, 0.f};

  // ---- prologue: tile0 fully + tile1 fully (8 loads each) ----
  stage_half(sA,        gA,                    K, tid);
  stage_half(sA + 8192, gA + (size_t)128 * K,  K, tid);
  stage_half(sB,        gB,                    K, tid);
  stage_half(sB + 8192, gB + (size_t)128 * K,  K, tid);
  if (NT > 1) {
    stage_half(sB + 16384,        gB + 64,                   K, tid);
    stage_half(sB + 16384 + 8192, gB + (size_t)128 * K + 64, K, tid);
    stage_half(sA + 16384,        gA + 64,                   K, tid);
    stage_half(sA + 16384 + 8192, gA + (size_t)128 * K + 64, K, tid);
    asm volatile("s_waitcnt vmcnt(8)" ::: "memory");
  } else {
    asm volatile("s_waitcnt vmcnt(0)" ::: "memory");
  }
  __builtin_amdgcn_s_barrier();

  for (int t = 0; t < NT; ++t) {
    const int d = t & 1;
    u16* aB = sA + d * 16384 + wm * 8192;
    u16* bB = sB + d * 16384 + (wn >> 1) * 8192 + (wn & 1) * 4096;

    s16x8 aF[4][2], bF[4][2];

    // ---------- phase 1: quad (mh0, nh0) ----------
    #pragma unroll
    for (int j = 0; j < 2; ++j) {
      bF[j][0] = *(const s16x8*)(bB + j * 1024 + rowoff + xt0);
      bF[j][1] = *(const s16x8*)(bB + j * 1024 + rowoff + xt1);
    }
    #pragma unroll
    for (int i = 0; i < 4; ++i) {
      aF[i][0] = *(const s16x8*)(aB + i * 1024 + rowoff + xt0);
      aF[i][1] = *(const s16x8*)(aB + i * 1024 + rowoff + xt1);
    }
    __builtin_amdgcn_s_barrier();
    asm volatile("s_waitcnt lgkmcnt(0)" ::: "memory");
    __builtin_amdgcn_s_setprio(1);
    MFMA_QUAD(0, 0)
    __builtin_amdgcn_s_setprio(0);
    __builtin_amdgcn_s_barrier();

    // ---------- phase 2: quad (mh0, nh1) ----------
    #pragma unroll
    for (int j = 2; j < 4; ++j) {
      bF[j][0] = *(const s16x8*)(bB + j * 1024 + rowoff + xt0);
      bF[j][1] = *(const s16x8*)(bB + j * 1024 + rowoff + xt1);
    }
    __builtin_amdgcn_s_barrier();
    asm volatile("s_waitcnt lgkmcnt(0)" ::: "memory");
    __builtin_amdgcn_s_setprio(1);
    MFMA_QUAD(0, 2)
    __builtin_amdgcn_s_setprio(0);
    __builtin_amdgcn_s_barrier();

    // ---------- phase 3: quad (mh1, nh0); stage B01(t+2) ----------
    #pragma unroll
    for (int i = 0; i < 4; ++i) {
      aF[i][0] = *(const s16x8*)(aB + 4096 + i * 1024 + rowoff + xt0);
      aF[i][1] = *(const s16x8*)(aB + 4096 + i * 1024 + rowoff + xt1);
    }
    if (t + 2 < NT) {
      stage_half(sB + d * 16384,        gB + (size_t)(t + 2) * 64,                   K, tid);
      stage_half(sB + d * 16384 + 8192, gB + (size_t)128 * K + (size_t)(t + 2) * 64, K, tid);
    }
    __builtin_amdgcn_s_barrier();
    asm volatile("s_waitcnt lgkmcnt(0)" ::: "memory");
    __builtin_amdgcn_s_setprio(1);
    MFMA_QUAD(4, 0)
    __builtin_amdgcn_s_setprio(0);
    __builtin_amdgcn_s_barrier();

    // ---------- phase 4: quad (mh1, nh1); stage A0+A1(t+2) ----------
    if (t + 2 < NT) {
      stage_half(sA + d * 16384,        gA + (size_t)(t + 2) * 64,                   K, tid);
      stage_half(sA + d * 16384 + 8192, gA + (size_t)128 * K + (size_t)(t + 2) * 64, K, tid);
    }
    __builtin_amdgcn_s_barrier();
    asm volatile("s_waitcnt lgkmcnt(0)" ::: "memory");
    __builtin_amdgcn_s_setprio(1);
    MFMA_QUAD(4, 2)
    __builtin_amdgcn_s_setprio(0);
    if (t + 2 < NT) asm volatile("s_waitcnt vmcnt(8)" ::: "memory");
    else            asm volatile("s_waitcnt vmcnt(0)" ::: "memory");
    __builtin_amdgcn_s_barrier();
  }

  #pragma unroll
  for (int i = 0; i < 8; ++i)
    #pragma unroll
    for (int j = 0; j < 4; ++j)
      #pragma unroll
      for (int r = 0; r < 4; ++r) {
        int m = m0 + wm * 128 + i * 16 + lg * 4 + r;
        int n = n0 + wn * 64 + j * 16 + lc;
        float v = acc[i][j][r];
        if (EPI == 0) {
          v = fminf(fmaxf(v, -CLIPV), CLIPV);
          ((u16*)Cout)[(size_t)m * N + n] = f2bf(v);
        } else {
          ((float*)Cout)[(size_t)m * N + n] = v;
        }
      }
}

// ---------------- kernel 4: LN(q), LN(k) over D=4096 + head relayout of q,k ----------------
__device__ inline void unpack8(uint4 u, float* f) {
  const u16* p = (const u16*)&u;
  #pragma unroll
  for (int j = 0; j < 8; ++j) f[j] = bf2f(p[j]);
}

__global__ void k_ln_reorder(const u16* __restrict__ qkv,
                             const float* __restrict__ qw, const float* __restrict__ qb,
                             const float* __restrict__ kw, const float* __restrict__ kb,
                             u16* __restrict__ Qo, u16* __restrict__ Ko) {
  const int row = blockIdx.x;               // 0..B*S-1
  const int b = row >> 11, s = row & 2047;
  const int t = threadIdx.x;
  const int lane = t & 63, w = t >> 6;
  const uint4* base = (const uint4*)(qkv + (size_t)row * (3 * DD));  // 1536 x uint4

  __shared__ float redsum[8], redss[8];

  uint4 q4[2], k4[2];
  q4[0] = base[t];        q4[1] = base[256 + t];
  k4[0] = base[512 + t];  k4[1] = base[768 + t];

  float qx[16], kx[16];
  unpack8(q4[0], qx); unpack8(q4[1], qx + 8);
  unpack8(k4[0], kx); unpack8(k4[1], kx + 8);

  float qs = 0.f, qss = 0.f, ks = 0.f, kss = 0.f;
  #pragma unroll
  for (int i = 0; i < 16; ++i) {
    qs += qx[i]; qss += qx[i] * qx[i];
    ks += kx[i]; kss += kx[i] * kx[i];
  }
  #pragma unroll
  for (int off = 1; off < 64; off <<= 1) {
    qs  += __shfl_xor(qs, off);  qss += __shfl_xor(qss, off);
    ks  += __shfl_xor(ks, off);  kss += __shfl_xor(kss, off);
  }
  if (lane == 0) { redsum[w] = qs; redss[w] = qss; redsum[4 + w] = ks; redss[4 + w] = kss; }
  __syncthreads();
  float qsum = redsum[0] + redsum[1] + redsum[2] + redsum[3];
  float qs2  = redss[0]  + redss[1]  + redss[2]  + redss[3];
  float ksum = redsum[4] + redsum[5] + redsum[6] + redsum[7];
  float ks2  = redss[4]  + redss[5]  + redss[6]  + redss[7];
  const float inv = 1.0f / (float)DD;
  float qmu = qsum * inv, qvar = qs2 * inv - qmu * qmu;
  float kmu = ksum * inv, kvar = ks2 * inv - kmu * kmu;
  float qrs = rsqrtf(qvar + LN_EPS_);
  float krs = rsqrtf(kvar + LN_EPS_);

  #pragma unroll
  for (int ch = 0; ch < 2; ++ch) {
    int c0 = ch * 2048 + t * 8;
    int hh = c0 >> 7, hd0 = c0 & 127;
    size_t idx = (((size_t)b * HH + hh) * SS + s) * HDD + hd0;
    {
      float4 w0 = *(const float4*)(qw + c0), w1 = *(const float4*)(qw + c0 + 4);
      float4 b0 = *(const float4*)(qb + c0), b1 = *(const float4*)(qb + c0 + 4);
      float wa[8] = {w0.x, w0.y, w0.z, w0.w, w1.x, w1.y, w1.z, w1.w};
      float ba[8] = {b0.x, b0.y, b0.z, b0.w, b1.x, b1.y, b1.z, b1.w};
      u16 tmp[8];
      #pragma unroll
      for (int j = 0; j < 8; ++j)
        tmp[j] = f2bf((qx[ch * 8 + j] - qmu) * qrs * wa[j] + ba[j]);
      *(uint4*)(Qo + idx) = *(const uint4*)tmp;
    }
    {
      float4 w0 = *(const float4*)(kw + c0), w1 = *(const float4*)(kw + c0 + 4);
      float4 b0 = *(const float4*)(kb + c0), b1 = *(const float4*)(kb + c0 + 4);
      float wa[8] = {w0.x, w0.y, w0.z, w0.w, w1.x, w1.y, w1.z, w1.w};
      float ba[8] = {b0.x, b0.y, b0.z, b0.w, b1.x, b1.y, b1.z, b1.w};
      u16 tmp[8];
      #pragma unroll
      for (int j = 0; j < 8; ++j)
        tmp[j] = f2bf((kx[ch * 8 + j] - kmu) * krs * wa[j] + ba[j]);
      *(uint4*)(Ko + idx) = *(const uint4*)tmp;
    }
  }
}

// ---------------- kernel 4b: V slice of qkv -> V^T [B][H][HD][S] ----------------
__global__ void k_transpose_v(const u16* __restrict__ qkv, u16* __restrict__ Vt) {
  __shared__ u16 ls[64 * 65];
  const int s0 = blockIdx.x * 64;
  const int hd0 = blockIdx.y * 64;
  const int bh = blockIdx.z;
  const int b = bh >> 5, h = bh & 31;
  const int t = threadIdx.x;
  const u16* src = qkv + (size_t)(b * SS + s0) * (3 * DD) + 2 * DD + h * HDD + hd0;
  #pragma unroll
  for (int it = 0; it < 4; ++it) {
    int idx = it * 256 + t;
    int sr = idx >> 4, hc = idx & 15;
    uint2 v = *(const uint2*)(src + (size_t)sr * (3 * DD) + hc * 4);
    const u16* pv = (const u16*)&v;
    #pragma unroll
    for (int j = 0; j < 4; ++j) ls[sr * 65 + hc * 4 + j] = pv[j];
  }
  __syncthreads();
  u16* dst = Vt + ((size_t)bh * HDD + hd0) * SS + s0;
  #pragma unroll
  for (int it = 0; it < 4; ++it) {
    int idx = it * 256 + t;
    int hd = idx >> 4, sc = idx & 15;
    u16 tmp[4];
    #pragma unroll
    for (int j = 0; j < 4; ++j) tmp[j] = ls[(4 * sc + j) * 65 + hd];
    *(uint2*)(dst + (size_t)hd * SS + 4 * sc) = *(const uint2*)tmp;
  }
}

// ---------------- kernel 5: flash attention with ALiBi + causal ----------------
// Double-buffered K/V staging: next tile's global_load_lds issued BEFORE this
// tile's QK/softmax/PV -> load latency hidden under compute. XCD swizzle:
// each XCD owns 8 contiguous bh (qt fastest) -> per-XCD K/V set L2-resident.
__global__ __launch_bounds__(256)
void k_attn(const u16* __restrict__ Qg, const u16* __restrict__ Kg,
            const u16* __restrict__ Vt, u16* __restrict__ Og) {
  const int bid = blockIdx.x;               // 2048 blocks
  const int id2 = ((bid & 7) << 8) + (bid >> 3);
  const int bh = id2 >> 5;                  // b*H + h  (8 bh per XCD)
  const int qt = id2 & 31;                  // q tile (64 rows)
  const int b = bh >> 5, h = bh & 31;
  const int t = threadIdx.x;
  const int lane = t & 63, w = t >> 6;
  const int lg = lane >> 4, lc = lane & 15;
  const float slope = exp2f(-0.25f * (float)(h + 1));

  __shared__ u16 lK[2][8192];               // [64 kv][128 d], 16B granule ^ (row&7)
  __shared__ u16 lV[2][8192];               // V^T [128 hd][64 kv], 16B granule ^ (row&7)
  __shared__ u16 lP[4][1024];               // per-wave P^T: [16 q][64 kv], 8B granule swz

  const int q0 = qt * 64 + w * 16;
  const size_t bhS = (size_t)bh * SS;
  const u16* Kbase = Kg + bhS * HDD;
  const u16* Vbase = Vt + bhS * HDD;        // [128 hd][2048 s] for this bh

  s16x8 qf[4];
  {
    const u16* qrow = Qg + (bhS + q0 + lc) * HDD;
    #pragma unroll
    for (int kt = 0; kt < 4; ++kt) qf[kt] = *(const s16x8*)(qrow + kt * 32 + lg * 8);
  }

  f32x4 ot[8];                              // O^T[hd = hf*16 + lg*4 + r][q = lc]
  #pragma unroll
  for (int hf = 0; hf < 8; ++hf) ot[hf] = (f32x4){0.f, 0.f, 0.f, 0.f};
  float m_r = -1e30f, l_r = 0.f;

  #define STAGE_KV(D, KV0)                                                         \
    {                                                                              \
      _Pragma("unroll")                                                            \
      for (int it_ = 0; it_ < 4; ++it_) {                                          \
        int sl = it_ * 256 + t;                                                    \
        int row = sl >> 4, k16 = sl & 15;                                          \
        gload_lds16(Kbase + (size_t)((KV0) + row) * HDD + ((k16 ^ (row & 7)) * 8), \
                    &lK[D][sl * 8]);                                               \
      }                                                                            \
      _Pragma("unroll")                                                            \
      for (int it_ = 0; it_ < 4; ++it_) {                                          \
        int sl = it_ * 256 + t;                                                    \
        int row = sl >> 3, k8 = sl & 7;                                            \
        gload_lds16(Vbase + (size_t)row * SS + (KV0) + ((k8 ^ (row & 7)) * 8),     \
                    &lV[D][sl * 8]);                                               \
      }                                                                            \
    }

  STAGE_KV(0, 0)
  __syncthreads();

  const int nt = qt + 1;
  for (int itn = 0; itn < nt; ++itn) {
    const int d = itn & 1;
    const int kv0 = itn * 64;
    if (itn + 1 < nt) STAGE_KV(d ^ 1, kv0 + 64)

    // QK^T (swapped): lane holds S^T(kv = i*16 + lg*4 + r, q = lc)
    f32x4 st[4];
    #pragma unroll
    for (int i = 0; i < 4; ++i) {
      st[i] = (f32x4){0.f, 0.f, 0.f, 0.f};
      #pragma unroll
      for (int kt = 0; kt < 4; ++kt) {
        int r = i * 16 + lc;
        const s16x8 ka = *(const s16x8*)&lK[d][r * 128 + (((kt * 4 + lg) ^ (r & 7)) * 8)];
        st[i] = mfma16(ka, qf[kt], st[i]);
      }
    }

    // scores + ALiBi + causal mask
    float sc[4][4];
    float pm = -1e30f;
    const int qg = q0 + lc;
    #pragma unroll
    for (int i = 0; i < 4; ++i)
      #pragma unroll
      for (int r = 0; r < 4; ++r) {
        int kv = kv0 + i * 16 + lg * 4 + r;
        float x = (kv <= qg) ? st[i][r] * SCALE_ - slope * (float)(qg - kv) : -1e30f;
        sc[i][r] = x;
        pm = fmaxf(pm, x);
      }
    pm = fmaxf(pm, __shfl_xor(pm, 16));
    pm = fmaxf(pm, __shfl_xor(pm, 32));
    float m_new = fmaxf(m_r, pm);
    float alpha = exp2f((m_r - m_new) * LOG2E_);
    float rsum = 0.f;
    #pragma unroll
    for (int i = 0; i < 4; ++i) {
      float p0 = exp2f((sc[i][0] - m_new) * LOG2E_);
      float p1 = exp2f((sc[i][1] - m_new) * LOG2E_);
      float p2 = exp2f((sc[i][2] - m_new) * LOG2E_);
      float p3 = exp2f((sc[i][3] - m_new) * LOG2E_);
      rsum += (p0 + p1) + (p2 + p3);
      u32 dlo, dhi;
      asm("v_cvt_pk_bf16_f32 %0, %1, %2" : "=v"(dlo) : "v"(p0), "v"(p1));
      asm("v_cvt_pk_bf16_f32 %0, %1, %2" : "=v"(dhi) : "v"(p2), "v"(p3));
      int addr = lc * 64 + (((4 * i + lg) ^ (2 * (lc & 7))) * 4);
      uint2 val; val.x = dlo; val.y = dhi;
      *(uint2*)&lP[w][addr] = val;
    }
    rsum += __shfl_xor(rsum, 16);
    rsum += __shfl_xor(rsum, 32);
    l_r = l_r * alpha + rsum;
    m_r = m_new;

    #pragma unroll
    for (int hf = 0; hf < 8; ++hf) {
      ot[hf][0] *= alpha; ot[hf][1] *= alpha; ot[hf][2] *= alpha; ot[hf][3] *= alpha;
    }

    // PV: O^T[hd][q] += V^T[hd][kv] * P^T[kv][q]
    #pragma unroll
    for (int ks = 0; ks < 2; ++ks) {
      const int m = 4 * ks + lg;            // 16B granule along kv
      const s16x8 pa = *(const s16x8*)&lP[w][lc * 64 + ((m ^ (lc & 7)) * 8)];
      #pragma unroll
      for (int hf = 0; hf < 8; ++hf) {
        int row = hf * 16 + lc;
        const s16x8 vb = *(const s16x8*)&lV[d][row * 64 + ((m ^ (row & 7)) * 8)];
        ot[hf] = mfma16(vb, pa, ot[hf]);
      }
    }
    __syncthreads();   // drains vmcnt(0) too -> next-tile staging complete
  }
  #undef STAGE_KV

  // epilogue: normalize by l (lane-local), store 8B chunks (4 contiguous hd)
  float linv = 1.f / l_r;
  const size_t obase = ((size_t)(b * SS + q0 + lc)) * DD + h * HDD;
  #pragma unroll
  for (int hf = 0; hf < 8; ++hf) {
    u16 tmp[4];
    #pragma unroll
    for (int r = 0; r < 4; ++r) tmp[r] = f2bf(ot[hf][r] * linv);
    *(uint2*)&Og[obase + hf * 16 + lg * 4] = *(const uint2*)tmp;
  }
}

// ---------------- launch ----------------
extern "C" void kernel_launch(void* const* d_in, const int* in_sizes, int n_in,
                              void* d_out, int out_size, void* d_ws, size_t ws_size,
                              hipStream_t stream) {
  const float* hidden = (const float*)d_in[0];
  const float* Wqkv   = (const float*)d_in[1];
  const float* Wout   = (const float*)d_in[2];
  const float* qw     = (const float*)d_in[3];
  const float* qb     = (const float*)d_in[4];
  const float* kw     = (const float*)d_in[5];
  const float* kb     = (const float*)d_in[6];
  float* out = (float*)d_out;
  char* ws = (char*)d_ws;

  // workspace layout (total 256 MB)
  u16* Xb    = (u16*)(ws);                    // 32 MB (reused as attn_out)
  u16* WqkvT = (u16*)(ws + 33554432);         // 96 MB (reused as Q,K,Vt after GEMM)
  u16* Qb    = (u16*)(ws + 33554432);
  u16* Kb    = (u16*)(ws + 67108864);
  u16* Vtb   = (u16*)(ws + 100663296);        // V^T [B][H][HD][S]
  u16* WoutT = (u16*)(ws + 134217728);        // 32 MB
  u16* qkv   = (u16*)(ws + 167772160);        // 96 MB
  u16* attnO = Xb;

  k_cvt_bf16<<<8192, 256, 0, stream>>>(hidden, Xb, 2097152);
  k_transpose_cvt<<<dim3(12288 / 32, 4096 / 32), 256, 0, stream>>>(Wqkv, WqkvT, 4096, 12288);
  k_transpose_cvt<<<dim3(4096 / 32, 4096 / 32), 256, 0, stream>>>(Wout, WoutT, 4096, 4096);
  // QKV GEMM: M=4096, N=12288, K=4096 -> grid 768, nBY=16
  k_gemm256<0><<<768, 512, 0, stream>>>(Xb, WqkvT, qkv, 4096, 12288, 4096, 16);
  k_ln_reorder<<<4096, 256, 0, stream>>>(qkv, qw, qb, kw, kb, Qb, Kb);
  k_transpose_v<<<dim3(SS / 64, HDD / 64, BB * HH), 256, 0, stream>>>(qkv, Vtb);
  k_attn<<<2048, 256, 0, stream>>>(Qb, Kb, Vtb, attnO);
  // out-proj GEMM: M=4096, N=4096, K=4096 -> grid 256, nBY=16
  k_gemm256<1><<<256, 512, 0, stream>>>(attnO, WoutT, out, 4096, 4096, 4096, 16);
}